// Round 1
// baseline (751.282 us; speedup 1.0000x reference)
//
#include <hip/hip_runtime.h>
#include <hip/hip_cooperative_groups.h>

namespace cg = cooperative_groups;

#define BB 8
#define LL 200
#define HH 128
#define NHEAD 4
#define HDIM 32
#define NBLK 2
#define BL (BB * LL)
#define NT 257            // TIME_SPAN+1
#define QT 8              // attn queries per tile
#define NQT 25            // 200/8
#define SSP 208           // attn score row stride
#define KTP 66            // attn KstT row stride
#define TSP 132           // GEMM tile row stride [r][k]

static constexpr float SQRT_H    = 11.313708498984761f;   // sqrt(128)
static constexpr float INV_SCALE = 0.17677669529663687f;  // 1/sqrt(32)
static constexpr float PADV      = -4294967295.0f;        // -2^32+1

// Shared-memory union sizes (floats):
//   qkv : 32*TSP + 16*TSP               = 6336
//   attn: 256+2112+2056+1664+256+1600   = 7944
//   ff  : 16*TSP*2 + 32                 = 4256
#define SMEM_WORDS 8192   // 32 KB -> 4 blocks/CU with __launch_bounds__(256,4)

struct MegaArgs {
    const int*   log_seqs;
    const int*   tm;
    const int*   pos_seqs;
    const int*   neg_seqs;
    const float* item_emb;
    const float* posK;
    const float* posV;
    const float* timeK;
    const float* timeV;
    const float* attn_g; const float* attn_b;
    const float* Wq; const float* bq;
    const float* Wk; const float* bk;
    const float* Wv; const float* bv;
    const float* fwd_g; const float* fwd_b;
    const float* W1; const float* b1;
    const float* W2; const float* b2;
    const float* last_g; const float* last_b;
    float* seqs; float* Qin; float* Q; float* K; float* V; float* att; float* h1;
    float* out;
};

// ===== QKV GEMM tile: 32x16, tile in [0,1200) ==============================
__device__ __forceinline__ void qkv_tile(float* smem, int tile, int tid,
        const float* seqs_in, const int* __restrict__ log_seqs,
        const float* __restrict__ item_emb,
        const float* __restrict__ g, const float* __restrict__ bia,
        const float* __restrict__ Wq, const float* __restrict__ bq,
        const float* __restrict__ Wk, const float* __restrict__ bk,
        const float* __restrict__ Wv, const float* __restrict__ bv,
        const float* __restrict__ posK, const float* __restrict__ posV,
        float* __restrict__ Qin, float* __restrict__ Q,
        float* __restrict__ K, float* __restrict__ V) {
    float* As = smem;              // 32*TSP
    float* Bs = smem + 32 * TSP;   // 16*TSP
    int mt = tile / 24, nt = tile % 24;
    int matsel = nt >> 3;          // 0=Q 1=K 2=V
    int jb = (nt & 7) * 16;
    int row0 = mt * 32;

    {   // stage A: 32 rows x 128, 8 threads/row; LN for Q-tiles
        int r = tid >> 3, seg = tid & 7;
        int row = row0 + r;
        float4 vv[4];
        if (seqs_in) {
            #pragma unroll
            for (int i = 0; i < 4; i++)
                vv[i] = *(const float4*)(seqs_in + (size_t)row * HH + seg * 16 + i * 4);
        } else {
            int idx = log_seqs[row];
            if (idx == 0) {
                #pragma unroll
                for (int i = 0; i < 4; i++) vv[i] = make_float4(0.f, 0.f, 0.f, 0.f);
            } else {
                #pragma unroll
                for (int i = 0; i < 4; i++) {
                    float4 e = *(const float4*)(item_emb + (size_t)idx * HH + seg * 16 + i * 4);
                    vv[i] = make_float4(e.x * SQRT_H, e.y * SQRT_H, e.z * SQRT_H, e.w * SQRT_H);
                }
            }
        }
        if (matsel == 0) {
            float s = 0.f, s2 = 0.f;
            #pragma unroll
            for (int i = 0; i < 4; i++) {
                s  += vv[i].x + vv[i].y + vv[i].z + vv[i].w;
                s2 += vv[i].x * vv[i].x + vv[i].y * vv[i].y + vv[i].z * vv[i].z + vv[i].w * vv[i].w;
            }
            #pragma unroll
            for (int off = 1; off < 8; off <<= 1) {
                s  += __shfl_xor(s, off);
                s2 += __shfl_xor(s2, off);
            }
            float mean = s * (1.f / HH);
            float var  = s2 * (1.f / HH) - mean * mean;
            float inv  = 1.f / sqrtf(var + 1e-8f);
            #pragma unroll
            for (int i = 0; i < 4; i++) {
                int k = seg * 16 + i * 4;
                float4 g4 = *(const float4*)(g + k);
                float4 b4 = *(const float4*)(bia + k);
                float4 y;
                y.x = (vv[i].x - mean) * inv * g4.x + b4.x;
                y.y = (vv[i].y - mean) * inv * g4.y + b4.y;
                y.z = (vv[i].z - mean) * inv * g4.z + b4.z;
                y.w = (vv[i].w - mean) * inv * g4.w + b4.w;
                *(float4*)&As[r * TSP + k] = y;
                if (nt == 0) *(float4*)(Qin + (size_t)row * HH + k) = y;
            }
        } else {
            #pragma unroll
            for (int i = 0; i < 4; i++)
                *(float4*)&As[r * TSP + seg * 16 + i * 4] = vv[i];
        }
    }
    {   // stage B: 16 W-rows x 128 k
        const float* W = (matsel == 0) ? Wq : (matsel == 1) ? Wk : Wv;
        int j = tid >> 4, seg = tid & 15;
        float4 w  = *(const float4*)(W + (size_t)(jb + j) * HH + seg * 8);
        float4 w2 = *(const float4*)(W + (size_t)(jb + j) * HH + seg * 8 + 4);
        *(float4*)&Bs[j * TSP + seg * 8]     = w;
        *(float4*)&Bs[j * TSP + seg * 8 + 4] = w2;
    }
    __syncthreads();

    int m = tid >> 3, jg = tid & 7;    // 2 output cols per thread
    float acc0 = 0.f, acc1 = 0.f;
    const float* ar  = &As[m * TSP];
    const float* b0r = &Bs[(jg * 2) * TSP];
    const float* b1r = &Bs[(jg * 2 + 1) * TSP];
    #pragma unroll 4
    for (int k4 = 0; k4 < 32; k4++) {
        float4 a  = *(const float4*)(ar + k4 * 4);
        float4 b0 = *(const float4*)(b0r + k4 * 4);
        float4 b1 = *(const float4*)(b1r + k4 * 4);
        acc0 += a.x * b0.x + a.y * b0.y + a.z * b0.z + a.w * b0.w;
        acc1 += a.x * b1.x + a.y * b1.y + a.z * b1.z + a.w * b1.w;
    }
    int row = row0 + m;
    int col = jb + jg * 2;
    int l = row % LL;
    if (matsel == 0) {
        float2 bb = *(const float2*)(bq + col);
        *(float2*)(Q + (size_t)row * HH + col) =
            make_float2((acc0 + bb.x) * INV_SCALE, (acc1 + bb.y) * INV_SCALE);
    } else if (matsel == 1) {
        float2 bb = *(const float2*)(bk + col);
        float2 pk = *(const float2*)(posK + (size_t)l * HH + col);
        *(float2*)(K + (size_t)row * HH + col) =
            make_float2(acc0 + bb.x + pk.x, acc1 + bb.y + pk.y);
    } else {
        float2 bb = *(const float2*)(bv + col);
        float2 pv = *(const float2*)(posV + (size_t)l * HH + col);
        *(float2*)(V + (size_t)row * HH + col) =
            make_float2(acc0 + bb.x + pv.x, acc1 + bb.y + pv.y);
    }
}

// ===== attention tile: tile = (qt-reversed)<<5 | (b<<2|n), tile in [0,800) =
__device__ __forceinline__ void attn_tile(float* smem, int tile, int tid,
        const float* __restrict__ Q, const float* __restrict__ K,
        const float* __restrict__ V,
        const float* __restrict__ timeK, const float* __restrict__ timeV,
        const int* __restrict__ tm, float* __restrict__ att) {
    float* Qs   = smem;            // 256
    float* KstT = smem + 256;      // 2112
    float* DTW  = KstT + 2112;     // 2056
    float* Ssc  = DTW + 2056;      // 1664
    float* Ost  = Ssc + 1664;      // 256
    int*   tmst = (int*)(Ost + 256); // 1600 ints

    int bn = tile & 31;
    int b = bn >> 2, n = bn & 3;
    int qt = (NQT - 1) - (tile >> 5);
    int q0 = qt * QT;
    int kmax = q0 + QT - 1;
    int wv = tid >> 6, ln = tid & 63;

    Ost[tid] = 0.f;
    if (tid < 64) {
        int qi = tid >> 3, d4 = tid & 7;
        *(float4*)(Qs + qi * HDIM + d4 * 4) =
            *(const float4*)(Q + ((size_t)(b * LL + q0 + qi)) * HH + n * HDIM + d4 * 4);
    }
    #pragma unroll
    for (int qi = 0; qi < QT; qi++)
        if (tid < LL)
            tmst[qi * LL + tid] = tm[((size_t)(b * LL + q0 + qi)) * LL + tid];
    __syncthreads();

    int k2 = tid & 31, qi_c = tid >> 5;

    // DT[qi][tau] = Qh . timeKh[tau]
    for (int c = 0; c < 5; c++) {
        #pragma unroll
        for (int p = 0; p < 2; p++) {
            int idx = tid + p * 256;
            int r = idx >> 3, d4 = idx & 7;
            int tau = c * 64 + r;
            float4 w = make_float4(0.f, 0.f, 0.f, 0.f);
            if (tau < NT) w = *(const float4*)(timeK + (size_t)tau * HH + n * HDIM + d4 * 4);
            KstT[(d4 * 4 + 0) * KTP + r] = w.x;
            KstT[(d4 * 4 + 1) * KTP + r] = w.y;
            KstT[(d4 * 4 + 2) * KTP + r] = w.z;
            KstT[(d4 * 4 + 3) * KTP + r] = w.w;
        }
        __syncthreads();
        float a0 = 0.f, a1 = 0.f;
        #pragma unroll 4
        for (int d = 0; d < HDIM; d++) {
            float qv = Qs[qi_c * HDIM + d];
            float2 kv = *(const float2*)&KstT[d * KTP + k2 * 2];
            a0 += qv * kv.x; a1 += qv * kv.y;
        }
        int tau0 = c * 64 + k2 * 2;
        if (tau0 < NT)     DTW[qi_c * NT + tau0]     = a0;
        if (tau0 + 1 < NT) DTW[qi_c * NT + tau0 + 1] = a1;
        __syncthreads();
    }

    // S[qi][k] = Qh.Kh[k] + DT[qi][tm[k]], causal
    int nch = (kmax >> 6) + 1;
    for (int c = 0; c < nch; c++) {
        #pragma unroll
        for (int p = 0; p < 2; p++) {
            int idx = tid + p * 256;
            int r = idx >> 3, d4 = idx & 7;
            int k = c * 64 + r;
            float4 w = make_float4(0.f, 0.f, 0.f, 0.f);
            if (k < LL) w = *(const float4*)(K + ((size_t)(b * LL + k)) * HH + n * HDIM + d4 * 4);
            KstT[(d4 * 4 + 0) * KTP + r] = w.x;
            KstT[(d4 * 4 + 1) * KTP + r] = w.y;
            KstT[(d4 * 4 + 2) * KTP + r] = w.z;
            KstT[(d4 * 4 + 3) * KTP + r] = w.w;
        }
        __syncthreads();
        float a0 = 0.f, a1 = 0.f;
        #pragma unroll 4
        for (int d = 0; d < HDIM; d++) {
            float qv = Qs[qi_c * HDIM + d];
            float2 kv = *(const float2*)&KstT[d * KTP + k2 * 2];
            a0 += qv * kv.x; a1 += qv * kv.y;
        }
        int q = q0 + qi_c;
        int k0 = c * 64 + k2 * 2;
        if (k0 <= kmax)
            Ssc[qi_c * SSP + k0] = (k0 <= q) ? (a0 + DTW[qi_c * NT + tmst[qi_c * LL + k0]]) : PADV;
        if (k0 + 1 <= kmax)
            Ssc[qi_c * SSP + k0 + 1] = (k0 + 1 <= q) ? (a1 + DTW[qi_c * NT + tmst[qi_c * LL + k0 + 1]]) : PADV;
        __syncthreads();
    }

    for (int idx = tid; idx < QT * NT; idx += 256) DTW[idx] = 0.f;
    __syncthreads();

    // softmax + scatter W (DTW reused as bins)
    for (int rr = 0; rr < 2; rr++) {
        int qi = wv + rr * 4;
        int q = q0 + qi;
        float sv[4];
        float m = PADV;
        #pragma unroll
        for (int jj = 0; jj < 4; jj++) {
            int k = ln + 64 * jj;
            sv[jj] = (k <= q) ? Ssc[qi * SSP + k] : PADV;
            m = fmaxf(m, sv[jj]);
        }
        for (int off = 32; off; off >>= 1) m = fmaxf(m, __shfl_xor(m, off));
        float sum = 0.f;
        #pragma unroll
        for (int jj = 0; jj < 4; jj++) {
            int k = ln + 64 * jj;
            sv[jj] = (k <= q) ? __expf(sv[jj] - m) : 0.f;
            sum += sv[jj];
        }
        for (int off = 32; off; off >>= 1) sum += __shfl_xor(sum, off);
        float inv = 1.f / sum;
        #pragma unroll
        for (int jj = 0; jj < 4; jj++) {
            int k = ln + 64 * jj;
            float p = sv[jj] * inv;
            if (k < SSP) Ssc[qi * SSP + k] = (k <= q) ? p : 0.f;
            if (k <= q) atomicAdd(&DTW[qi * NT + tmst[qi * LL + k]], p);
        }
    }
    __syncthreads();

    // O = P@Vh + W@timeVh
    int d = tid & 31, kg = tid >> 5;
    float acc[QT] = {0,0,0,0,0,0,0,0};
    const float* vb = V + ((size_t)(b * LL)) * HH + n * HDIM + d;
    for (int k = kg; k <= kmax; k += 8) {
        float v = vb[(size_t)k * HH];
        #pragma unroll
        for (int qi = 0; qi < QT; qi++) acc[qi] += Ssc[qi * SSP + k] * v;
    }
    const float* tvb = timeV + n * HDIM + d;
    for (int t = kg; t < NT; t += 8) {
        float v = tvb[(size_t)t * HH];
        #pragma unroll
        for (int qi = 0; qi < QT; qi++) acc[qi] += DTW[qi * NT + t] * v;
    }
    #pragma unroll
    for (int qi = 0; qi < QT; qi++) atomicAdd(&Ost[qi * HDIM + d], acc[qi]);
    __syncthreads();
    {
        int qi = tid >> 5;
        att[((size_t)(b * LL + q0 + qi)) * HH + n * HDIM + (tid & 31)] = Ost[tid];
    }
}

// ===== FF1 tile: h1 = relu(LN(Qin+att)@W1^T + b1), tile in [0,800) =========
__device__ __forceinline__ void ff1_tile(float* smem, int tile, int tid,
        const float* __restrict__ Qin, const float* __restrict__ att,
        const float* __restrict__ g, const float* __restrict__ bia,
        const float* __restrict__ W1, const float* __restrict__ b1,
        float* __restrict__ h1) {
    float* As = smem;
    float* Bs = smem + 16 * TSP;
    int mt = tile >> 3, jb = (tile & 7) * 16;
    int row0 = mt * 16;

    {   // stage A = LN(Qin+att), 16 threads/row
        int r = tid >> 4, seg = tid & 15;
        int row = row0 + r;
        float4 vv[2];
        #pragma unroll
        for (int i = 0; i < 2; i++) {
            int k = seg * 8 + i * 4;
            float4 q4 = *(const float4*)(Qin + (size_t)row * HH + k);
            float4 a4 = *(const float4*)(att + (size_t)row * HH + k);
            vv[i] = make_float4(q4.x + a4.x, q4.y + a4.y, q4.z + a4.z, q4.w + a4.w);
        }
        float s = 0.f, s2 = 0.f;
        #pragma unroll
        for (int i = 0; i < 2; i++) {
            s  += vv[i].x + vv[i].y + vv[i].z + vv[i].w;
            s2 += vv[i].x * vv[i].x + vv[i].y * vv[i].y + vv[i].z * vv[i].z + vv[i].w * vv[i].w;
        }
        #pragma unroll
        for (int off = 1; off < 16; off <<= 1) {
            s  += __shfl_xor(s, off);
            s2 += __shfl_xor(s2, off);
        }
        float mean = s * (1.f / HH);
        float var  = s2 * (1.f / HH) - mean * mean;
        float inv  = 1.f / sqrtf(var + 1e-8f);
        #pragma unroll
        for (int i = 0; i < 2; i++) {
            int k = seg * 8 + i * 4;
            float4 g4 = *(const float4*)(g + k);
            float4 b4 = *(const float4*)(bia + k);
            float4 y;
            y.x = (vv[i].x - mean) * inv * g4.x + b4.x;
            y.y = (vv[i].y - mean) * inv * g4.y + b4.y;
            y.z = (vv[i].z - mean) * inv * g4.z + b4.z;
            y.w = (vv[i].w - mean) * inv * g4.w + b4.w;
            *(float4*)&As[r * TSP + k] = y;
        }
    }
    {   // stage B
        int j = tid >> 4, seg = tid & 15;
        *(float4*)&Bs[j * TSP + seg * 8]     = *(const float4*)(W1 + (size_t)(jb + j) * HH + seg * 8);
        *(float4*)&Bs[j * TSP + seg * 8 + 4] = *(const float4*)(W1 + (size_t)(jb + j) * HH + seg * 8 + 4);
    }
    __syncthreads();

    int m = tid >> 4, j = tid & 15;
    float acc = 0.f;
    const float* ar = &As[m * TSP];
    const float* br = &Bs[j * TSP];
    #pragma unroll 4
    for (int k4 = 0; k4 < 32; k4++) {
        float4 a = *(const float4*)(ar + k4 * 4);
        float4 b = *(const float4*)(br + k4 * 4);
        acc += a.x * b.x + a.y * b.y + a.z * b.z + a.w * b.w;
    }
    int col = jb + j;
    float t = acc + b1[col];
    h1[(size_t)(row0 + m) * HH + col] = t > 0.f ? t : 0.f;
}

// ===== FF2 tile: out = (h1@W2^T + b2 + LN(Qin+att))*keep, tile in [0,800) ==
__device__ __forceinline__ void ff2_tile(float* smem, int tile, int tid,
        const float* __restrict__ h1,
        const float* __restrict__ Qin, const float* __restrict__ att,
        const float* __restrict__ g, const float* __restrict__ bia,
        const float* __restrict__ W2, const float* __restrict__ b2,
        const int* __restrict__ log_seqs,
        float* __restrict__ out) {
    float* As   = smem;
    float* Bs   = smem + 16 * TSP;
    float* mu   = smem + 32 * TSP;
    float* rstd = mu + 16;
    int mt = tile >> 3, jb = (tile & 7) * 16;
    int row0 = mt * 16;

    {   // stage A = h1; compute residual row stats
        int r = tid >> 4, seg = tid & 15;
        int row = row0 + r;
        #pragma unroll
        for (int i = 0; i < 2; i++) {
            int k = seg * 8 + i * 4;
            *(float4*)&As[r * TSP + k] = *(const float4*)(h1 + (size_t)row * HH + k);
        }
        float s = 0.f, s2 = 0.f;
        #pragma unroll
        for (int i = 0; i < 2; i++) {
            int k = seg * 8 + i * 4;
            float4 q4 = *(const float4*)(Qin + (size_t)row * HH + k);
            float4 a4 = *(const float4*)(att + (size_t)row * HH + k);
            float4 v = make_float4(q4.x + a4.x, q4.y + a4.y, q4.z + a4.z, q4.w + a4.w);
            s  += v.x + v.y + v.z + v.w;
            s2 += v.x * v.x + v.y * v.y + v.z * v.z + v.w * v.w;
        }
        #pragma unroll
        for (int off = 1; off < 16; off <<= 1) {
            s  += __shfl_xor(s, off);
            s2 += __shfl_xor(s2, off);
        }
        float mean = s * (1.f / HH);
        float var  = s2 * (1.f / HH) - mean * mean;
        if (seg == 0) { mu[r] = mean; rstd[r] = 1.f / sqrtf(var + 1e-8f); }
    }
    {   // stage B
        int j = tid >> 4, seg = tid & 15;
        *(float4*)&Bs[j * TSP + seg * 8]     = *(const float4*)(W2 + (size_t)(jb + j) * HH + seg * 8);
        *(float4*)&Bs[j * TSP + seg * 8 + 4] = *(const float4*)(W2 + (size_t)(jb + j) * HH + seg * 8 + 4);
    }
    __syncthreads();

    int m = tid >> 4, j = tid & 15;
    float acc = 0.f;
    const float* ar = &As[m * TSP];
    const float* br = &Bs[j * TSP];
    #pragma unroll 4
    for (int k4 = 0; k4 < 32; k4++) {
        float4 a = *(const float4*)(ar + k4 * 4);
        float4 b = *(const float4*)(br + k4 * 4);
        acc += a.x * b.x + a.y * b.y + a.z * b.z + a.w * b.w;
    }
    int row = row0 + m;
    int col = jb + j;
    float resid = Qin[(size_t)row * HH + col] + att[(size_t)row * HH + col];
    float y = (resid - mu[m]) * rstd[m] * g[col] + bia[col];
    float o = acc + b2[col] + y;
    if (log_seqs[row] == 0) o = 0.f;
    out[(size_t)row * HH + col] = o;
}

// ===== last-LN + logits: 2 rows per 256-thr block, tile in [0,800) =========
__device__ __forceinline__ void lnlog_pair(float* smem, int tile, int tid,
        const float* __restrict__ seqs,
        const float* __restrict__ g, const float* __restrict__ bia,
        const float* __restrict__ item_emb,
        const int* __restrict__ pos, const int* __restrict__ neg,
        float* __restrict__ out) {
    int row = tile * 2 + (tid >> 7);
    int h = tid & 127;
    float v = seqs[(size_t)row * HH + h];
    float s = v, s2 = v * v;
    for (int off = 32; off; off >>= 1) {
        s  += __shfl_xor(s, off);
        s2 += __shfl_xor(s2, off);
    }
    float* r1 = smem;       // [4]
    float* r2 = smem + 4;   // [4]
    float* rp = smem + 8;   // [4]
    float* rn = smem + 12;  // [4]
    int w = tid >> 6;       // wave id 0..3
    if ((tid & 63) == 0) { r1[w] = s; r2[w] = s2; }
    __syncthreads();
    int wb = (tid >> 7) << 1;   // 0 for row0 (waves 0,1), 2 for row1 (waves 2,3)
    float mean = (r1[wb] + r1[wb + 1]) * (1.f / HH);
    float var  = (r2[wb] + r2[wb + 1]) * (1.f / HH) - mean * mean;
    float inv = 1.f / sqrtf(var + 1e-8f);
    float f = (v - mean) * inv * g[h] + bia[h];

    int ip = pos[row], in_ = neg[row];
    float vp = f * item_emb[(size_t)ip * HH + h];
    float vn = f * item_emb[(size_t)in_ * HH + h];
    for (int off = 32; off; off >>= 1) {
        vp += __shfl_xor(vp, off);
        vn += __shfl_xor(vn, off);
    }
    if ((tid & 63) == 0) { rp[w] = vp; rn[w] = vn; }
    __syncthreads();
    if ((tid & 127) == 0) {
        out[row]      = rp[wb] + rp[wb + 1];
        out[BL + row] = rn[wb] + rn[wb + 1];
    }
}

// ===== fused persistent cooperative kernel =================================
__global__ __launch_bounds__(256, 4) void k_tisas_mega(MegaArgs p) {
    cg::grid_group gg = cg::this_grid();
    __shared__ __align__(16) float smem[SMEM_WORDS];
    const int tid = threadIdx.x, bid = blockIdx.x, nb = gridDim.x;

    for (int i = 0; i < NBLK; i++) {
        const float* seqs_in = (i == 0) ? (const float*)nullptr : p.seqs;
        for (int t = bid; t < 1200; t += nb) {
            __syncthreads();
            qkv_tile(smem, t, tid, seqs_in, p.log_seqs, p.item_emb,
                     p.attn_g + i * HH, p.attn_b + i * HH,
                     p.Wq + (size_t)i * HH * HH, p.bq + i * HH,
                     p.Wk + (size_t)i * HH * HH, p.bk + i * HH,
                     p.Wv + (size_t)i * HH * HH, p.bv + i * HH,
                     p.posK, p.posV, p.Qin, p.Q, p.K, p.V);
        }
        gg.sync();
        for (int t = bid; t < NQT * 32; t += nb) {
            __syncthreads();
            attn_tile(smem, t, tid, p.Q, p.K, p.V, p.timeK, p.timeV, p.tm, p.att);
        }
        gg.sync();
        for (int t = bid; t < 800; t += nb) {
            __syncthreads();
            ff1_tile(smem, t, tid, p.Qin, p.att, p.fwd_g + i * HH, p.fwd_b + i * HH,
                     p.W1 + (size_t)i * HH * HH, p.b1 + i * HH, p.h1);
        }
        gg.sync();
        for (int t = bid; t < 800; t += nb) {
            __syncthreads();
            ff2_tile(smem, t, tid, p.h1, p.Qin, p.att, p.fwd_g + i * HH, p.fwd_b + i * HH,
                     p.W2 + (size_t)i * HH * HH, p.b2 + i * HH, p.log_seqs, p.seqs);
        }
        gg.sync();
    }
    for (int t = bid; t < 800; t += nb) {
        __syncthreads();
        lnlog_pair(smem, t, tid, p.seqs, p.last_g, p.last_b, p.item_emb,
                   p.pos_seqs, p.neg_seqs, p.out);
    }
}

// ===== fallback wrappers (old 9-launch path), reuse tile bodies ============
__global__ void k_qkv_gemm(const float* seqs_in, const int* log_seqs, const float* item_emb,
                           const float* g, const float* bia,
                           const float* Wq, const float* bq, const float* Wk, const float* bk,
                           const float* Wv, const float* bv,
                           const float* posK, const float* posV,
                           float* Qin, float* Q, float* K, float* V) {
    __shared__ __align__(16) float smem[48 * TSP];
    qkv_tile(smem, blockIdx.x, threadIdx.x, seqs_in, log_seqs, item_emb, g, bia,
             Wq, bq, Wk, bk, Wv, bv, posK, posV, Qin, Q, K, V);
}
__global__ void k_attn(const float* Q, const float* K, const float* V,
                       const float* timeK, const float* timeV, const int* tm, float* att) {
    __shared__ __align__(16) float smem[7944];
    attn_tile(smem, blockIdx.x, threadIdx.x, Q, K, V, timeK, timeV, tm, att);
}
__global__ void k_ff1(const float* Qin, const float* att, const float* g, const float* bia,
                      const float* W1, const float* b1, float* h1) {
    __shared__ __align__(16) float smem[32 * TSP + 32];
    ff1_tile(smem, blockIdx.x, threadIdx.x, Qin, att, g, bia, W1, b1, h1);
}
__global__ void k_ff2(const float* h1, const float* Qin, const float* att,
                      const float* g, const float* bia, const float* W2, const float* b2,
                      const int* log_seqs, float* out) {
    __shared__ __align__(16) float smem[32 * TSP + 32];
    ff2_tile(smem, blockIdx.x, threadIdx.x, h1, Qin, att, g, bia, W2, b2, log_seqs, out);
}
__global__ void k_lnlogits(const float* seqs, const float* g, const float* bia,
                           const float* item_emb, const int* pos, const int* neg,
                           float* out) {
    __shared__ __align__(16) float smem[16];
    lnlog_pair(smem, blockIdx.x, threadIdx.x, seqs, g, bia, item_emb, pos, neg, out);
}

extern "C" void kernel_launch(void* const* d_in, const int* in_sizes, int n_in,
                              void* d_out, int out_size, void* d_ws, size_t ws_size,
                              hipStream_t stream) {
    const int* log_seqs   = (const int*)d_in[1];
    const int* tm         = (const int*)d_in[2];
    const int* pos_seqs   = (const int*)d_in[3];
    const int* neg_seqs   = (const int*)d_in[4];
    const float* item_emb = (const float*)d_in[5];
    const float* posK     = (const float*)d_in[6];
    const float* posV     = (const float*)d_in[7];
    const float* timeK    = (const float*)d_in[8];
    const float* timeV    = (const float*)d_in[9];
    const float* attn_g   = (const float*)d_in[10];
    const float* attn_b   = (const float*)d_in[11];
    const float* Wq       = (const float*)d_in[12];
    const float* bq       = (const float*)d_in[13];
    const float* Wk       = (const float*)d_in[14];
    const float* bk       = (const float*)d_in[15];
    const float* Wv       = (const float*)d_in[16];
    const float* bv       = (const float*)d_in[17];
    const float* fwd_g    = (const float*)d_in[18];
    const float* fwd_b    = (const float*)d_in[19];
    const float* W1       = (const float*)d_in[20];
    const float* b1       = (const float*)d_in[21];
    const float* W2       = (const float*)d_in[22];
    const float* b2       = (const float*)d_in[23];
    const float* last_g   = (const float*)d_in[24];
    const float* last_b   = (const float*)d_in[25];

    float* seqs = (float*)d_ws;            // 7 x B*L*H f32 = ~5.7 MB
    float* Qin  = seqs + (size_t)BL * HH;
    float* Qb   = Qin  + (size_t)BL * HH;
    float* Kb   = Qb   + (size_t)BL * HH;
    float* Vb   = Kb   + (size_t)BL * HH;
    float* att  = Vb   + (size_t)BL * HH;
    float* h1   = att  + (size_t)BL * HH;

    MegaArgs a;
    a.log_seqs = log_seqs; a.tm = tm; a.pos_seqs = pos_seqs; a.neg_seqs = neg_seqs;
    a.item_emb = item_emb; a.posK = posK; a.posV = posV; a.timeK = timeK; a.timeV = timeV;
    a.attn_g = attn_g; a.attn_b = attn_b;
    a.Wq = Wq; a.bq = bq; a.Wk = Wk; a.bk = bk; a.Wv = Wv; a.bv = bv;
    a.fwd_g = fwd_g; a.fwd_b = fwd_b; a.W1 = W1; a.b1 = b1; a.W2 = W2; a.b2 = b2;
    a.last_g = last_g; a.last_b = last_b;
    a.seqs = seqs; a.Qin = Qin; a.Q = Qb; a.K = Kb; a.V = Vb; a.att = att; a.h1 = h1;
    a.out = (float*)d_out;

    // Co-residency-safe grid: 4 blocks/CU via __launch_bounds__(256,4) + 32 KB LDS.
    static int grid_sz = 0;
    if (grid_sz == 0) {
        int occ = 0;
        if (hipOccupancyMaxActiveBlocksPerMultiprocessor(&occ, k_tisas_mega, 256, 0)
                != hipSuccess || occ < 1)
            occ = 2;                       // conservative floor: 2/CU always fits
        long gmax = (long)occ * 256;       // 256 CUs on MI355X
        grid_sz = (int)(gmax < 1024 ? gmax : 1024);
    }

    void* args[] = { (void*)&a };
    hipError_t err = hipLaunchCooperativeKernel(k_tisas_mega, dim3(grid_sz), dim3(256),
                                                args, 0, stream);
    if (err != hipSuccess) {
        // Fallback: verified 9-launch path
        for (int i = 0; i < NBLK; i++) {
            k_qkv_gemm<<<1200, 256, 0, stream>>>(i == 0 ? nullptr : seqs, log_seqs, item_emb,
                                                 attn_g + i * HH, attn_b + i * HH,
                                                 Wq + (size_t)i * HH * HH, bq + i * HH,
                                                 Wk + (size_t)i * HH * HH, bk + i * HH,
                                                 Wv + (size_t)i * HH * HH, bv + i * HH,
                                                 posK, posV, Qin, Qb, Kb, Vb);
            k_attn<<<NQT * 32, 256, 0, stream>>>(Qb, Kb, Vb, timeK, timeV, tm, att);
            k_ff1<<<800, 256, 0, stream>>>(Qin, att, fwd_g + i * HH, fwd_b + i * HH,
                                           W1 + (size_t)i * HH * HH, b1 + i * HH, h1);
            k_ff2<<<800, 256, 0, stream>>>(h1, Qin, att, fwd_g + i * HH, fwd_b + i * HH,
                                           W2 + (size_t)i * HH * HH, b2 + i * HH,
                                           log_seqs, seqs);
        }
        k_lnlogits<<<800, 256, 0, stream>>>(seqs, last_g, last_b, item_emb,
                                            pos_seqs, neg_seqs, (float*)d_out);
    }
}

// Round 2
// 302.038 us; speedup vs baseline: 2.4874x; 2.4874x over previous
//
#include <hip/hip_runtime.h>

#define BB 8
#define LL 200
#define HH 128
#define NHEAD 4
#define HDIM 32
#define NBLK 2
#define BL (BB * LL)
#define NT 257            // TIME_SPAN+1
#define QT 8              // attn queries per tile
#define NQT 25            // 200/8
#define SSP 208           // attn score row stride
#define TSP 132           // GEMM tile row stride [r][k]

static constexpr float SQRT_H    = 11.313708498984761f;   // sqrt(128)
static constexpr float INV_SCALE = 0.17677669529663687f;  // 1/sqrt(32)
static constexpr float PADV      = -4294967295.0f;        // -2^32+1

// ===== QKV GEMM: 32x16 tiles, 50 Mt x 24 Nt = 1200 blocks, 256 thr ========
// nt 0-7 -> Q (A=LN(x), *INV_SCALE), 8-15 -> K (+posK), 16-23 -> V (+posV)
__global__ void k_qkv_gemm(const float* __restrict__ seqs_in,
                           const int* __restrict__ log_seqs,
                           const float* __restrict__ item_emb,
                           const float* __restrict__ g, const float* __restrict__ bia,
                           const float* __restrict__ Wq, const float* __restrict__ bq,
                           const float* __restrict__ Wk, const float* __restrict__ bk,
                           const float* __restrict__ Wv, const float* __restrict__ bv,
                           const float* __restrict__ posK, const float* __restrict__ posV,
                           float* __restrict__ Qin, float* __restrict__ Q,
                           float* __restrict__ K, float* __restrict__ V) {
    int mt = blockIdx.x / 24, nt = blockIdx.x % 24;
    int matsel = nt >> 3;              // 0=Q 1=K 2=V
    int jb = (nt & 7) * 16;
    int row0 = mt * 32;
    int tid = threadIdx.x;
    __shared__ float As[32 * TSP];     // 16.9 KB [m][k]
    __shared__ float Bs[16 * TSP];     //  8.4 KB [j][k]

    {   // stage A: 32 rows x 128, 8 threads/row; LN for Q-tiles
        int r = tid >> 3, seg = tid & 7;
        int row = row0 + r;
        float4 vv[4];
        if (seqs_in) {
            #pragma unroll
            for (int i = 0; i < 4; i++)
                vv[i] = *(const float4*)(seqs_in + (size_t)row * HH + seg * 16 + i * 4);
        } else {
            int idx = log_seqs[row];
            if (idx == 0) {
                #pragma unroll
                for (int i = 0; i < 4; i++) vv[i] = make_float4(0.f, 0.f, 0.f, 0.f);
            } else {
                #pragma unroll
                for (int i = 0; i < 4; i++) {
                    float4 e = *(const float4*)(item_emb + (size_t)idx * HH + seg * 16 + i * 4);
                    vv[i] = make_float4(e.x * SQRT_H, e.y * SQRT_H, e.z * SQRT_H, e.w * SQRT_H);
                }
            }
        }
        if (matsel == 0) {
            float s = 0.f, s2 = 0.f;
            #pragma unroll
            for (int i = 0; i < 4; i++) {
                s  += vv[i].x + vv[i].y + vv[i].z + vv[i].w;
                s2 += vv[i].x * vv[i].x + vv[i].y * vv[i].y + vv[i].z * vv[i].z + vv[i].w * vv[i].w;
            }
            #pragma unroll
            for (int off = 1; off < 8; off <<= 1) {
                s  += __shfl_xor(s, off);
                s2 += __shfl_xor(s2, off);
            }
            float mean = s * (1.f / HH);
            float var  = s2 * (1.f / HH) - mean * mean;
            float inv  = 1.f / sqrtf(var + 1e-8f);
            #pragma unroll
            for (int i = 0; i < 4; i++) {
                int k = seg * 16 + i * 4;
                float4 g4 = *(const float4*)(g + k);
                float4 b4 = *(const float4*)(bia + k);
                float4 y;
                y.x = (vv[i].x - mean) * inv * g4.x + b4.x;
                y.y = (vv[i].y - mean) * inv * g4.y + b4.y;
                y.z = (vv[i].z - mean) * inv * g4.z + b4.z;
                y.w = (vv[i].w - mean) * inv * g4.w + b4.w;
                *(float4*)&As[r * TSP + k] = y;
                if (nt == 0) *(float4*)(Qin + (size_t)row * HH + k) = y;
            }
        } else {
            #pragma unroll
            for (int i = 0; i < 4; i++)
                *(float4*)&As[r * TSP + seg * 16 + i * 4] = vv[i];
        }
    }
    {   // stage B: 16 W-rows x 128 k
        const float* W = (matsel == 0) ? Wq : (matsel == 1) ? Wk : Wv;
        int j = tid >> 4, seg = tid & 15;
        float4 w  = *(const float4*)(W + (size_t)(jb + j) * HH + seg * 8);
        float4 w2 = *(const float4*)(W + (size_t)(jb + j) * HH + seg * 8 + 4);
        *(float4*)&Bs[j * TSP + seg * 8]     = w;
        *(float4*)&Bs[j * TSP + seg * 8 + 4] = w2;
    }
    __syncthreads();

    int m = tid >> 3, jg = tid & 7;    // 2 output cols per thread
    float acc0 = 0.f, acc1 = 0.f;
    const float* ar  = &As[m * TSP];
    const float* b0r = &Bs[(jg * 2) * TSP];
    const float* b1r = &Bs[(jg * 2 + 1) * TSP];
    #pragma unroll 4
    for (int k4 = 0; k4 < 32; k4++) {
        float4 a  = *(const float4*)(ar + k4 * 4);
        float4 b0 = *(const float4*)(b0r + k4 * 4);
        float4 b1 = *(const float4*)(b1r + k4 * 4);
        acc0 += a.x * b0.x + a.y * b0.y + a.z * b0.z + a.w * b0.w;
        acc1 += a.x * b1.x + a.y * b1.y + a.z * b1.z + a.w * b1.w;
    }
    int row = row0 + m;
    int col = jb + jg * 2;
    int l = row % LL;
    if (matsel == 0) {
        float2 bb = *(const float2*)(bq + col);
        *(float2*)(Q + (size_t)row * HH + col) =
            make_float2((acc0 + bb.x) * INV_SCALE, (acc1 + bb.y) * INV_SCALE);
    } else if (matsel == 1) {
        float2 bb = *(const float2*)(bk + col);
        float2 pk = *(const float2*)(posK + (size_t)l * HH + col);
        *(float2*)(K + (size_t)row * HH + col) =
            make_float2(acc0 + bb.x + pk.x, acc1 + bb.y + pk.y);
    } else {
        float2 bb = *(const float2*)(bv + col);
        float2 pv = *(const float2*)(posV + (size_t)l * HH + col);
        *(float2*)(V + (size_t)row * HH + col) =
            make_float2(acc0 + bb.x + pv.x, acc1 + bb.y + pv.y);
    }
}

// ===== attention v2: ILP-oriented, 5 barriers/block ========================
// block = (b, head, 8-q tile), 256 thr. Q row cached in regs; K/timeK read
// directly from global (L1/L2-resident slices) with deep load ILP instead of
// LDS chunk staging (removes 9 stage->sync->dot->sync cycles).
__global__ void k_attn(const float* __restrict__ Q, const float* __restrict__ K,
                       const float* __restrict__ V,
                       const float* __restrict__ timeK, const float* __restrict__ timeV,
                       const int* __restrict__ tm,
                       float* __restrict__ att) {
    int bn = blockIdx.x & 31;
    int b = bn >> 2, n = bn & 3;
    int qt = (NQT - 1) - (blockIdx.x >> 5);   // heavy tiles first
    int q0 = qt * QT;
    int kmax = q0 + QT - 1;
    int tid = threadIdx.x;
    int wv = tid >> 6, ln = tid & 63;

    __shared__ float DTW[QT * NT];     // 8.2 KB: DT table, then scatter bins
    __shared__ float Ssc[QT * SSP];    // 6.7 KB
    __shared__ float Ost[QT * HDIM];   // 1.0 KB
    __shared__ int   tmst[QT * LL];    // 6.4 KB

    // stage time-matrix rows (no barrier needed until after DT phase)
    #pragma unroll
    for (int qi = 0; qi < QT; qi++)
        if (tid < LL)
            tmst[qi * LL + tid] = tm[((size_t)(b * LL + q0 + qi)) * LL + tid];
    Ost[tid] = 0.f;

    int k2 = tid & 31, qi_c = tid >> 5;
    int q = q0 + qi_c;

    // Q row -> 32 registers (lanes of same qi read same line: broadcast)
    float qreg[HDIM];
    {
        const float* qp = Q + ((size_t)(b * LL + q)) * HH + n * HDIM;
        #pragma unroll
        for (int i = 0; i < 8; i++) {
            float4 v = *(const float4*)(qp + i * 4);
            qreg[i * 4 + 0] = v.x; qreg[i * 4 + 1] = v.y;
            qreg[i * 4 + 2] = v.z; qreg[i * 4 + 3] = v.w;
        }
    }

    // DT[qi][tau] = Qh . timeKh[tau]; 9 independent guarded dots/thread
    #pragma unroll
    for (int j = 0; j < 9; j++) {
        int tau = k2 + 32 * j;
        if (tau < NT) {
            const float* tk = timeK + (size_t)tau * HH + n * HDIM;
            float a = 0.f;
            #pragma unroll
            for (int i = 0; i < 8; i++) {
                float4 w = *(const float4*)(tk + i * 4);
                a += qreg[i * 4 + 0] * w.x + qreg[i * 4 + 1] * w.y
                   + qreg[i * 4 + 2] * w.z + qreg[i * 4 + 3] * w.w;
            }
            DTW[qi_c * NT + tau] = a;
        }
    }
    __syncthreads();   // DTW complete, tmst visible

    // S[qi][k] = Qh.Kh[k] + DT[qi][tm[k]] for k <= q (others never read)
    #pragma unroll
    for (int j = 0; j < 7; j++) {
        int k = k2 + 32 * j;
        if (k <= q) {
            const float* kp = K + ((size_t)(b * LL + k)) * HH + n * HDIM;
            float a = 0.f;
            #pragma unroll
            for (int i = 0; i < 8; i++) {
                float4 w = *(const float4*)(kp + i * 4);
                a += qreg[i * 4 + 0] * w.x + qreg[i * 4 + 1] * w.y
                   + qreg[i * 4 + 2] * w.z + qreg[i * 4 + 3] * w.w;
            }
            Ssc[qi_c * SSP + k] = a + DTW[qi_c * NT + tmst[qi_c * LL + k]];
        }
    }
    __syncthreads();   // Ssc complete; DTW free to be re-purposed

    for (int idx = tid; idx < QT * NT; idx += 256) DTW[idx] = 0.f;
    __syncthreads();

    // softmax + scatter W (DTW reused as time-bins)
    for (int rr = 0; rr < 2; rr++) {
        int qi = wv + rr * 4;
        int qq = q0 + qi;
        float sv[4];
        float m = PADV;
        #pragma unroll
        for (int jj = 0; jj < 4; jj++) {
            int k = ln + 64 * jj;
            sv[jj] = (k <= qq) ? Ssc[qi * SSP + k] : PADV;
            m = fmaxf(m, sv[jj]);
        }
        for (int off = 32; off; off >>= 1) m = fmaxf(m, __shfl_xor(m, off));
        float sum = 0.f;
        #pragma unroll
        for (int jj = 0; jj < 4; jj++) {
            int k = ln + 64 * jj;
            sv[jj] = (k <= qq) ? __expf(sv[jj] - m) : 0.f;
            sum += sv[jj];
        }
        for (int off = 32; off; off >>= 1) sum += __shfl_xor(sum, off);
        float inv = 1.f / sum;
        #pragma unroll
        for (int jj = 0; jj < 4; jj++) {
            int k = ln + 64 * jj;
            float p = sv[jj] * inv;
            if (k < SSP) Ssc[qi * SSP + k] = (k <= qq) ? p : 0.f;
            if (k <= qq) atomicAdd(&DTW[qi * NT + tmst[qi * LL + k]], p);
        }
    }
    __syncthreads();

    // O = P@Vh + W@timeVh
    int d = tid & 31, kg = tid >> 5;
    float acc[QT] = {0,0,0,0,0,0,0,0};
    const float* vb = V + ((size_t)(b * LL)) * HH + n * HDIM + d;
    for (int k = kg; k <= kmax; k += 8) {
        float v = vb[(size_t)k * HH];
        #pragma unroll
        for (int qi = 0; qi < QT; qi++) acc[qi] += Ssc[qi * SSP + k] * v;
    }
    const float* tvb = timeV + n * HDIM + d;
    for (int t = kg; t < NT; t += 8) {
        float v = tvb[(size_t)t * HH];
        #pragma unroll
        for (int qi = 0; qi < QT; qi++) acc[qi] += DTW[qi * NT + t] * v;
    }
    #pragma unroll
    for (int qi = 0; qi < QT; qi++) atomicAdd(&Ost[qi * HDIM + d], acc[qi]);
    __syncthreads();
    {
        int qi = tid >> 5;
        att[((size_t)(b * LL + q0 + qi)) * HH + n * HDIM + (tid & 31)] = Ost[tid];
    }
}

// ===== FF1: h1 = relu(LN(Qin+att)@W1^T + b1), 16x16 tiles, 800 blocks =====
__global__ void k_ff1(const float* __restrict__ Qin, const float* __restrict__ att,
                      const float* __restrict__ g, const float* __restrict__ bia,
                      const float* __restrict__ W1, const float* __restrict__ b1,
                      float* __restrict__ h1) {
    int mt = blockIdx.x >> 3, jb = (blockIdx.x & 7) * 16;
    int row0 = mt * 16;
    int tid = threadIdx.x;
    __shared__ float As[16 * TSP];
    __shared__ float Bs[16 * TSP];

    {   // stage A = LN(Qin+att), 16 threads/row
        int r = tid >> 4, seg = tid & 15;
        int row = row0 + r;
        float4 vv[2];
        #pragma unroll
        for (int i = 0; i < 2; i++) {
            int k = seg * 8 + i * 4;
            float4 q4 = *(const float4*)(Qin + (size_t)row * HH + k);
            float4 a4 = *(const float4*)(att + (size_t)row * HH + k);
            vv[i] = make_float4(q4.x + a4.x, q4.y + a4.y, q4.z + a4.z, q4.w + a4.w);
        }
        float s = 0.f, s2 = 0.f;
        #pragma unroll
        for (int i = 0; i < 2; i++) {
            s  += vv[i].x + vv[i].y + vv[i].z + vv[i].w;
            s2 += vv[i].x * vv[i].x + vv[i].y * vv[i].y + vv[i].z * vv[i].z + vv[i].w * vv[i].w;
        }
        #pragma unroll
        for (int off = 1; off < 16; off <<= 1) {
            s  += __shfl_xor(s, off);
            s2 += __shfl_xor(s2, off);
        }
        float mean = s * (1.f / HH);
        float var  = s2 * (1.f / HH) - mean * mean;
        float inv  = 1.f / sqrtf(var + 1e-8f);
        #pragma unroll
        for (int i = 0; i < 2; i++) {
            int k = seg * 8 + i * 4;
            float4 g4 = *(const float4*)(g + k);
            float4 b4 = *(const float4*)(bia + k);
            float4 y;
            y.x = (vv[i].x - mean) * inv * g4.x + b4.x;
            y.y = (vv[i].y - mean) * inv * g4.y + b4.y;
            y.z = (vv[i].z - mean) * inv * g4.z + b4.z;
            y.w = (vv[i].w - mean) * inv * g4.w + b4.w;
            *(float4*)&As[r * TSP + k] = y;
        }
    }
    {   // stage B
        int j = tid >> 4, seg = tid & 15;
        *(float4*)&Bs[j * TSP + seg * 8]     = *(const float4*)(W1 + (size_t)(jb + j) * HH + seg * 8);
        *(float4*)&Bs[j * TSP + seg * 8 + 4] = *(const float4*)(W1 + (size_t)(jb + j) * HH + seg * 8 + 4);
    }
    __syncthreads();

    int m = tid >> 4, j = tid & 15;
    float acc = 0.f;
    const float* ar = &As[m * TSP];
    const float* br = &Bs[j * TSP];
    #pragma unroll 4
    for (int k4 = 0; k4 < 32; k4++) {
        float4 a = *(const float4*)(ar + k4 * 4);
        float4 b = *(const float4*)(br + k4 * 4);
        acc += a.x * b.x + a.y * b.y + a.z * b.z + a.w * b.w;
    }
    int col = jb + j;
    float t = acc + b1[col];
    h1[(size_t)(row0 + m) * HH + col] = t > 0.f ? t : 0.f;
}

// ===== FF2: out = (h1@W2^T + b2 + LN(Qin+att))*keep, 16x16, 800 blocks ====
__global__ void k_ff2(const float* __restrict__ h1,
                      const float* __restrict__ Qin, const float* __restrict__ att,
                      const float* __restrict__ g, const float* __restrict__ bia,
                      const float* __restrict__ W2, const float* __restrict__ b2,
                      const int* __restrict__ log_seqs,
                      float* __restrict__ out) {
    int mt = blockIdx.x >> 3, jb = (blockIdx.x & 7) * 16;
    int row0 = mt * 16;
    int tid = threadIdx.x;
    __shared__ float As[16 * TSP];
    __shared__ float Bs[16 * TSP];
    __shared__ float mu[16], rstd[16];

    {   // stage A = h1; compute residual row stats
        int r = tid >> 4, seg = tid & 15;
        int row = row0 + r;
        #pragma unroll
        for (int i = 0; i < 2; i++) {
            int k = seg * 8 + i * 4;
            *(float4*)&As[r * TSP + k] = *(const float4*)(h1 + (size_t)row * HH + k);
        }
        float s = 0.f, s2 = 0.f;
        #pragma unroll
        for (int i = 0; i < 2; i++) {
            int k = seg * 8 + i * 4;
            float4 q4 = *(const float4*)(Qin + (size_t)row * HH + k);
            float4 a4 = *(const float4*)(att + (size_t)row * HH + k);
            float4 v = make_float4(q4.x + a4.x, q4.y + a4.y, q4.z + a4.z, q4.w + a4.w);
            s  += v.x + v.y + v.z + v.w;
            s2 += v.x * v.x + v.y * v.y + v.z * v.z + v.w * v.w;
        }
        #pragma unroll
        for (int off = 1; off < 16; off <<= 1) {
            s  += __shfl_xor(s, off);
            s2 += __shfl_xor(s2, off);
        }
        float mean = s * (1.f / HH);
        float var  = s2 * (1.f / HH) - mean * mean;
        if (seg == 0) { mu[r] = mean; rstd[r] = 1.f / sqrtf(var + 1e-8f); }
    }
    {   // stage B
        int j = tid >> 4, seg = tid & 15;
        *(float4*)&Bs[j * TSP + seg * 8]     = *(const float4*)(W2 + (size_t)(jb + j) * HH + seg * 8);
        *(float4*)&Bs[j * TSP + seg * 8 + 4] = *(const float4*)(W2 + (size_t)(jb + j) * HH + seg * 8 + 4);
    }
    __syncthreads();

    int m = tid >> 4, j = tid & 15;
    float acc = 0.f;
    const float* ar = &As[m * TSP];
    const float* br = &Bs[j * TSP];
    #pragma unroll 4
    for (int k4 = 0; k4 < 32; k4++) {
        float4 a = *(const float4*)(ar + k4 * 4);
        float4 b = *(const float4*)(br + k4 * 4);
        acc += a.x * b.x + a.y * b.y + a.z * b.z + a.w * b.w;
    }
    int row = row0 + m;
    int col = jb + j;
    float resid = Qin[(size_t)row * HH + col] + att[(size_t)row * HH + col];
    float y = (resid - mu[m]) * rstd[m] * g[col] + bia[col];
    float o = acc + b2[col] + y;
    if (log_seqs[row] == 0) o = 0.f;
    out[(size_t)row * HH + col] = o;
}

// ===== fused last-LN + pos/neg logits: one block per row ==================
__global__ void k_lnlogits(const float* __restrict__ seqs,
                           const float* __restrict__ g, const float* __restrict__ bia,
                           const float* __restrict__ item_emb,
                           const int* __restrict__ pos, const int* __restrict__ neg,
                           float* __restrict__ out) {
    int row = blockIdx.x;
    int h = threadIdx.x;
    float v = seqs[(size_t)row * HH + h];
    float s = v, s2 = v * v;
    for (int off = 32; off; off >>= 1) {
        s  += __shfl_xor(s, off);
        s2 += __shfl_xor(s2, off);
    }
    __shared__ float r1[2], r2[2];
    if ((h & 63) == 0) { r1[h >> 6] = s; r2[h >> 6] = s2; }
    __syncthreads();
    float mean = (r1[0] + r1[1]) * (1.f / HH);
    float var  = (r2[0] + r2[1]) * (1.f / HH) - mean * mean;
    float inv = 1.f / sqrtf(var + 1e-8f);
    float f = (v - mean) * inv * g[h] + bia[h];

    int ip = pos[row], in_ = neg[row];
    float vp = f * item_emb[(size_t)ip * HH + h];
    float vn = f * item_emb[(size_t)in_ * HH + h];
    for (int off = 32; off; off >>= 1) {
        vp += __shfl_xor(vp, off);
        vn += __shfl_xor(vn, off);
    }
    __shared__ float rp[2], rn[2];
    if ((h & 63) == 0) { rp[h >> 6] = vp; rn[h >> 6] = vn; }
    __syncthreads();
    if (h == 0) {
        out[row]      = rp[0] + rp[1];
        out[BL + row] = rn[0] + rn[1];
    }
}

extern "C" void kernel_launch(void* const* d_in, const int* in_sizes, int n_in,
                              void* d_out, int out_size, void* d_ws, size_t ws_size,
                              hipStream_t stream) {
    const int* log_seqs   = (const int*)d_in[1];
    const int* tm         = (const int*)d_in[2];
    const int* pos_seqs   = (const int*)d_in[3];
    const int* neg_seqs   = (const int*)d_in[4];
    const float* item_emb = (const float*)d_in[5];
    const float* posK     = (const float*)d_in[6];
    const float* posV     = (const float*)d_in[7];
    const float* timeK    = (const float*)d_in[8];
    const float* timeV    = (const float*)d_in[9];
    const float* attn_g   = (const float*)d_in[10];
    const float* attn_b   = (const float*)d_in[11];
    const float* Wq       = (const float*)d_in[12];
    const float* bq       = (const float*)d_in[13];
    const float* Wk       = (const float*)d_in[14];
    const float* bk       = (const float*)d_in[15];
    const float* Wv       = (const float*)d_in[16];
    const float* bv       = (const float*)d_in[17];
    const float* fwd_g    = (const float*)d_in[18];
    const float* fwd_b    = (const float*)d_in[19];
    const float* W1       = (const float*)d_in[20];
    const float* b1       = (const float*)d_in[21];
    const float* W2       = (const float*)d_in[22];
    const float* b2       = (const float*)d_in[23];
    const float* last_g   = (const float*)d_in[24];
    const float* last_b   = (const float*)d_in[25];

    float* seqs = (float*)d_ws;            // 7 x B*L*H f32 = ~5.7 MB
    float* Qin  = seqs + (size_t)BL * HH;
    float* Qb   = Qin  + (size_t)BL * HH;
    float* Kb   = Qb   + (size_t)BL * HH;
    float* Vb   = Kb   + (size_t)BL * HH;
    float* att  = Vb   + (size_t)BL * HH;
    float* h1   = att  + (size_t)BL * HH;

    for (int i = 0; i < NBLK; i++) {
        k_qkv_gemm<<<1200, 256, 0, stream>>>(i == 0 ? nullptr : seqs, log_seqs, item_emb,
                                             attn_g + i * HH, attn_b + i * HH,
                                             Wq + (size_t)i * HH * HH, bq + i * HH,
                                             Wk + (size_t)i * HH * HH, bk + i * HH,
                                             Wv + (size_t)i * HH * HH, bv + i * HH,
                                             posK, posV, Qin, Qb, Kb, Vb);
        k_attn<<<NQT * 32, 256, 0, stream>>>(Qb, Kb, Vb, timeK, timeV, tm, att);
        k_ff1<<<800, 256, 0, stream>>>(Qin, att, fwd_g + i * HH, fwd_b + i * HH,
                                       W1 + (size_t)i * HH * HH, b1 + i * HH, h1);
        k_ff2<<<800, 256, 0, stream>>>(h1, Qin, att, fwd_g + i * HH, fwd_b + i * HH,
                                       W2 + (size_t)i * HH * HH, b2 + i * HH,
                                       log_seqs, seqs);
    }
    k_lnlogits<<<BL, HH, 0, stream>>>(seqs, last_g, last_b, item_emb,
                                      pos_seqs, neg_seqs, (float*)d_out);
}

// Round 3
// 236.381 us; speedup vs baseline: 3.1783x; 1.2778x over previous
//
#include <hip/hip_runtime.h>

#define BB 8
#define LL 200
#define HH 128
#define NHEAD 4
#define HDIM 32
#define NBLK 2
#define BL (BB * LL)
#define NT 257            // TIME_SPAN+1
#define QT 8              // attn queries per tile
#define NQT 25            // 200/8
#define SSP 208           // attn score row stride
#define KTP 66            // attn KstT row stride
#define TSP 132           // GEMM tile row stride [r][k]

static constexpr float SQRT_H    = 11.313708498984761f;   // sqrt(128)
static constexpr float INV_SCALE = 0.17677669529663687f;  // 1/sqrt(32)
static constexpr float PADV      = -4294967295.0f;        // -2^32+1

// ===== QKV GEMM: 32x16 tiles, 50 Mt x 24 Nt = 1200 blocks, 256 thr ========
// nt 0-7 -> Q (A=LN(x), *INV_SCALE), 8-15 -> K (+posK), 16-23 -> V (+posV)
__global__ void k_qkv_gemm(const float* __restrict__ seqs_in,
                           const int* __restrict__ log_seqs,
                           const float* __restrict__ item_emb,
                           const float* __restrict__ g, const float* __restrict__ bia,
                           const float* __restrict__ Wq, const float* __restrict__ bq,
                           const float* __restrict__ Wk, const float* __restrict__ bk,
                           const float* __restrict__ Wv, const float* __restrict__ bv,
                           const float* __restrict__ posK, const float* __restrict__ posV,
                           float* __restrict__ Qin, float* __restrict__ Q,
                           float* __restrict__ K, float* __restrict__ V) {
    int mt = blockIdx.x / 24, nt = blockIdx.x % 24;
    int matsel = nt >> 3;              // 0=Q 1=K 2=V
    int jb = (nt & 7) * 16;
    int row0 = mt * 32;
    int tid = threadIdx.x;
    __shared__ float As[32 * TSP];     // 16.9 KB [m][k]
    __shared__ float Bs[16 * TSP];     //  8.4 KB [j][k]

    {   // stage A: 32 rows x 128, 8 threads/row; LN for Q-tiles
        int r = tid >> 3, seg = tid & 7;
        int row = row0 + r;
        float4 vv[4];
        if (seqs_in) {
            #pragma unroll
            for (int i = 0; i < 4; i++)
                vv[i] = *(const float4*)(seqs_in + (size_t)row * HH + seg * 16 + i * 4);
        } else {
            int idx = log_seqs[row];
            if (idx == 0) {
                #pragma unroll
                for (int i = 0; i < 4; i++) vv[i] = make_float4(0.f, 0.f, 0.f, 0.f);
            } else {
                #pragma unroll
                for (int i = 0; i < 4; i++) {
                    float4 e = *(const float4*)(item_emb + (size_t)idx * HH + seg * 16 + i * 4);
                    vv[i] = make_float4(e.x * SQRT_H, e.y * SQRT_H, e.z * SQRT_H, e.w * SQRT_H);
                }
            }
        }
        if (matsel == 0) {
            float s = 0.f, s2 = 0.f;
            #pragma unroll
            for (int i = 0; i < 4; i++) {
                s  += vv[i].x + vv[i].y + vv[i].z + vv[i].w;
                s2 += vv[i].x * vv[i].x + vv[i].y * vv[i].y + vv[i].z * vv[i].z + vv[i].w * vv[i].w;
            }
            #pragma unroll
            for (int off = 1; off < 8; off <<= 1) {
                s  += __shfl_xor(s, off);
                s2 += __shfl_xor(s2, off);
            }
            float mean = s * (1.f / HH);
            float var  = s2 * (1.f / HH) - mean * mean;
            float inv  = 1.f / sqrtf(var + 1e-8f);
            #pragma unroll
            for (int i = 0; i < 4; i++) {
                int k = seg * 16 + i * 4;
                float4 g4 = *(const float4*)(g + k);
                float4 b4 = *(const float4*)(bia + k);
                float4 y;
                y.x = (vv[i].x - mean) * inv * g4.x + b4.x;
                y.y = (vv[i].y - mean) * inv * g4.y + b4.y;
                y.z = (vv[i].z - mean) * inv * g4.z + b4.z;
                y.w = (vv[i].w - mean) * inv * g4.w + b4.w;
                *(float4*)&As[r * TSP + k] = y;
                if (nt == 0) *(float4*)(Qin + (size_t)row * HH + k) = y;
            }
        } else {
            #pragma unroll
            for (int i = 0; i < 4; i++)
                *(float4*)&As[r * TSP + seg * 16 + i * 4] = vv[i];
        }
    }
    {   // stage B: 16 W-rows x 128 k
        const float* W = (matsel == 0) ? Wq : (matsel == 1) ? Wk : Wv;
        int j = tid >> 4, seg = tid & 15;
        float4 w  = *(const float4*)(W + (size_t)(jb + j) * HH + seg * 8);
        float4 w2 = *(const float4*)(W + (size_t)(jb + j) * HH + seg * 8 + 4);
        *(float4*)&Bs[j * TSP + seg * 8]     = w;
        *(float4*)&Bs[j * TSP + seg * 8 + 4] = w2;
    }
    __syncthreads();

    int m = tid >> 3, jg = tid & 7;    // 2 output cols per thread
    float acc0 = 0.f, acc1 = 0.f;
    const float* ar  = &As[m * TSP];
    const float* b0r = &Bs[(jg * 2) * TSP];
    const float* b1r = &Bs[(jg * 2 + 1) * TSP];
    #pragma unroll 4
    for (int k4 = 0; k4 < 32; k4++) {
        float4 a  = *(const float4*)(ar + k4 * 4);
        float4 b0 = *(const float4*)(b0r + k4 * 4);
        float4 b1 = *(const float4*)(b1r + k4 * 4);
        acc0 += a.x * b0.x + a.y * b0.y + a.z * b0.z + a.w * b0.w;
        acc1 += a.x * b1.x + a.y * b1.y + a.z * b1.z + a.w * b1.w;
    }
    int row = row0 + m;
    int col = jb + jg * 2;
    int l = row % LL;
    if (matsel == 0) {
        float2 bb = *(const float2*)(bq + col);
        *(float2*)(Q + (size_t)row * HH + col) =
            make_float2((acc0 + bb.x) * INV_SCALE, (acc1 + bb.y) * INV_SCALE);
    } else if (matsel == 1) {
        float2 bb = *(const float2*)(bk + col);
        float2 pk = *(const float2*)(posK + (size_t)l * HH + col);
        *(float2*)(K + (size_t)row * HH + col) =
            make_float2(acc0 + bb.x + pk.x, acc1 + bb.y + pk.y);
    } else {
        float2 bb = *(const float2*)(bv + col);
        float2 pv = *(const float2*)(posV + (size_t)l * HH + col);
        *(float2*)(V + (size_t)row * HH + col) =
            make_float2(acc0 + bb.x + pv.x, acc1 + bb.y + pv.y);
    }
}

// ===== attention v3: double-buffered chunk pipeline, 256 thr ===============
// block = (b, head, 8-q tile). Unified 9-chunk loop (5 timeK + up to 4 K),
// stage(c+1) overlaps dot(c); DT-add deferred to softmax; W@timeV replaced
// by coalesced per-(qi,k) timeV row gather fused into the PV loop.
__global__ void k_attn(const float* __restrict__ Q, const float* __restrict__ K,
                       const float* __restrict__ V,
                       const float* __restrict__ timeK, const float* __restrict__ timeV,
                       const int* __restrict__ tm,
                       float* __restrict__ att) {
    int bn = blockIdx.x & 31;
    int b = bn >> 2, n = bn & 3;
    int qt = (NQT - 1) - (blockIdx.x >> 5);
    int q0 = qt * QT;
    int kmax = q0 + QT - 1;
    int tid = threadIdx.x;
    int wv = tid >> 6, ln = tid & 63;

    __shared__ float KstT[2][HDIM * KTP];  // 2 x 8.4 KB staging (dbuf)
    __shared__ float DTW[QT * NT];         // 8.2 KB DT table
    __shared__ float Ssc[QT * SSP];        // 6.7 KB scores -> P
    __shared__ float Ost[QT * HDIM];       // 1.0 KB
    __shared__ int   tmst[QT * LL];        // 6.4 KB

    Ost[tid] = 0.f;
    #pragma unroll
    for (int qi = 0; qi < QT; qi++)
        if (tid < LL)
            tmst[qi * LL + tid] = tm[((size_t)(b * LL + q0 + qi)) * LL + tid];

    int k2 = tid & 31, qi_c = tid >> 5;
    int q = q0 + qi_c;

    // Q row -> 32 registers (per-thread; half-wave broadcast on L1)
    float qreg[HDIM];
    {
        const float* qp = Q + ((size_t)(b * LL + q)) * HH + n * HDIM;
        #pragma unroll
        for (int i = 0; i < 8; i++) {
            float4 v = *(const float4*)(qp + i * 4);
            qreg[i * 4 + 0] = v.x; qreg[i * 4 + 1] = v.y;
            qreg[i * 4 + 2] = v.z; qreg[i * 4 + 3] = v.w;
        }
    }

    const int nchS = (kmax >> 6) + 1;      // K chunks (1..4)
    const int ncht = 5 + nchS;             // total chunks

    // stage chunk c into buf: rows r=0..63 of timeK (c<5) or K (c>=5)
    auto stage = [&](int c, float* buf) {
        #pragma unroll
        for (int p = 0; p < 2; p++) {
            int idx = tid + p * 256;
            int r = idx >> 3, d4 = idx & 7;
            float4 w = make_float4(0.f, 0.f, 0.f, 0.f);
            if (c < 5) {
                int tau = c * 64 + r;
                if (tau < NT) w = *(const float4*)(timeK + (size_t)tau * HH + n * HDIM + d4 * 4);
            } else {
                int k = (c - 5) * 64 + r;
                if (k < LL) w = *(const float4*)(K + ((size_t)(b * LL + k)) * HH + n * HDIM + d4 * 4);
            }
            buf[(d4 * 4 + 0) * KTP + r] = w.x;
            buf[(d4 * 4 + 1) * KTP + r] = w.y;
            buf[(d4 * 4 + 2) * KTP + r] = w.z;
            buf[(d4 * 4 + 3) * KTP + r] = w.w;
        }
    };

    stage(0, KstT[0]);
    __syncthreads();
    for (int c = 0; c < ncht; c++) {
        if (c + 1 < ncht) stage(c + 1, KstT[(c + 1) & 1]);
        const float* buf = KstT[c & 1];
        float a0 = 0.f, a1 = 0.f;
        #pragma unroll 4
        for (int d = 0; d < HDIM; d++) {
            float qv = qreg[d];
            float2 kv = *(const float2*)&buf[d * KTP + k2 * 2];
            a0 += qv * kv.x; a1 += qv * kv.y;
        }
        if (c < 5) {
            int tau0 = c * 64 + k2 * 2;
            if (tau0 < NT)     DTW[qi_c * NT + tau0]     = a0;
            if (tau0 + 1 < NT) DTW[qi_c * NT + tau0 + 1] = a1;
        } else {
            int k0 = (c - 5) * 64 + k2 * 2;
            if (k0 <= kmax)     Ssc[qi_c * SSP + k0]     = a0;   // raw QK; DT added in softmax
            if (k0 + 1 <= kmax) Ssc[qi_c * SSP + k0 + 1] = a1;
        }
        __syncthreads();
    }

    // softmax with fused DT gather (LDS): sv = QK + DT[tm[k]]
    for (int rr = 0; rr < 2; rr++) {
        int qi = wv + rr * 4;
        int qq = q0 + qi;
        float sv[4];
        float m = PADV;
        #pragma unroll
        for (int jj = 0; jj < 4; jj++) {
            int k = ln + 64 * jj;
            sv[jj] = (k <= qq) ? (Ssc[qi * SSP + k] + DTW[qi * NT + tmst[qi * LL + k]]) : PADV;
            m = fmaxf(m, sv[jj]);
        }
        for (int off = 32; off; off >>= 1) m = fmaxf(m, __shfl_xor(m, off));
        float sum = 0.f;
        #pragma unroll
        for (int jj = 0; jj < 4; jj++) {
            int k = ln + 64 * jj;
            sv[jj] = (k <= qq) ? __expf(sv[jj] - m) : 0.f;
            sum += sv[jj];
        }
        for (int off = 32; off; off >>= 1) sum += __shfl_xor(sum, off);
        float inv = 1.f / sum;
        #pragma unroll
        for (int jj = 0; jj < 4; jj++) {
            int k = ln + 64 * jj;
            if (k < SSP) Ssc[qi * SSP + k] = (k <= qq) ? sv[jj] * inv : 0.f;
        }
    }
    __syncthreads();

    // O = P@(Vh + timeVh[tm]) — per-(qi,k) timeV row read is lane-coalesced
    int d = tid & 31, kg = tid >> 5;
    float acc[QT] = {0,0,0,0,0,0,0,0};
    const float* vb  = V + ((size_t)(b * LL)) * HH + n * HDIM + d;
    const float* tvb = timeV + n * HDIM + d;
    for (int k = kg; k <= kmax; k += 8) {
        float v = vb[(size_t)k * HH];
        #pragma unroll
        for (int qi = 0; qi < QT; qi++) {
            float p  = Ssc[qi * SSP + k];
            float tv = tvb[(size_t)tmst[qi * LL + k] * HH];
            acc[qi] += p * (v + tv);
        }
    }
    #pragma unroll
    for (int qi = 0; qi < QT; qi++) atomicAdd(&Ost[qi * HDIM + d], acc[qi]);
    __syncthreads();
    {
        int qi = tid >> 5;
        att[((size_t)(b * LL + q0 + qi)) * HH + n * HDIM + (tid & 31)] = Ost[tid];
    }
}

// ===== FF1: h1 = relu(LN(Qin+att)@W1^T + b1), 16x16 tiles, 800 blocks =====
__global__ void k_ff1(const float* __restrict__ Qin, const float* __restrict__ att,
                      const float* __restrict__ g, const float* __restrict__ bia,
                      const float* __restrict__ W1, const float* __restrict__ b1,
                      float* __restrict__ h1) {
    int mt = blockIdx.x >> 3, jb = (blockIdx.x & 7) * 16;
    int row0 = mt * 16;
    int tid = threadIdx.x;
    __shared__ float As[16 * TSP];
    __shared__ float Bs[16 * TSP];

    {   // stage A = LN(Qin+att), 16 threads/row
        int r = tid >> 4, seg = tid & 15;
        int row = row0 + r;
        float4 vv[2];
        #pragma unroll
        for (int i = 0; i < 2; i++) {
            int k = seg * 8 + i * 4;
            float4 q4 = *(const float4*)(Qin + (size_t)row * HH + k);
            float4 a4 = *(const float4*)(att + (size_t)row * HH + k);
            vv[i] = make_float4(q4.x + a4.x, q4.y + a4.y, q4.z + a4.z, q4.w + a4.w);
        }
        float s = 0.f, s2 = 0.f;
        #pragma unroll
        for (int i = 0; i < 2; i++) {
            s  += vv[i].x + vv[i].y + vv[i].z + vv[i].w;
            s2 += vv[i].x * vv[i].x + vv[i].y * vv[i].y + vv[i].z * vv[i].z + vv[i].w * vv[i].w;
        }
        #pragma unroll
        for (int off = 1; off < 16; off <<= 1) {
            s  += __shfl_xor(s, off);
            s2 += __shfl_xor(s2, off);
        }
        float mean = s * (1.f / HH);
        float var  = s2 * (1.f / HH) - mean * mean;
        float inv  = 1.f / sqrtf(var + 1e-8f);
        #pragma unroll
        for (int i = 0; i < 2; i++) {
            int k = seg * 8 + i * 4;
            float4 g4 = *(const float4*)(g + k);
            float4 b4 = *(const float4*)(bia + k);
            float4 y;
            y.x = (vv[i].x - mean) * inv * g4.x + b4.x;
            y.y = (vv[i].y - mean) * inv * g4.y + b4.y;
            y.z = (vv[i].z - mean) * inv * g4.z + b4.z;
            y.w = (vv[i].w - mean) * inv * g4.w + b4.w;
            *(float4*)&As[r * TSP + k] = y;
        }
    }
    {   // stage B
        int j = tid >> 4, seg = tid & 15;
        *(float4*)&Bs[j * TSP + seg * 8]     = *(const float4*)(W1 + (size_t)(jb + j) * HH + seg * 8);
        *(float4*)&Bs[j * TSP + seg * 8 + 4] = *(const float4*)(W1 + (size_t)(jb + j) * HH + seg * 8 + 4);
    }
    __syncthreads();

    int m = tid >> 4, j = tid & 15;
    float acc = 0.f;
    const float* ar = &As[m * TSP];
    const float* br = &Bs[j * TSP];
    #pragma unroll 4
    for (int k4 = 0; k4 < 32; k4++) {
        float4 a = *(const float4*)(ar + k4 * 4);
        float4 b = *(const float4*)(br + k4 * 4);
        acc += a.x * b.x + a.y * b.y + a.z * b.z + a.w * b.w;
    }
    int col = jb + j;
    float t = acc + b1[col];
    h1[(size_t)(row0 + m) * HH + col] = t > 0.f ? t : 0.f;
}

// ===== FF2: out = (h1@W2^T + b2 + LN(Qin+att))*keep, 16x16, 800 blocks ====
__global__ void k_ff2(const float* __restrict__ h1,
                      const float* __restrict__ Qin, const float* __restrict__ att,
                      const float* __restrict__ g, const float* __restrict__ bia,
                      const float* __restrict__ W2, const float* __restrict__ b2,
                      const int* __restrict__ log_seqs,
                      float* __restrict__ out) {
    int mt = blockIdx.x >> 3, jb = (blockIdx.x & 7) * 16;
    int row0 = mt * 16;
    int tid = threadIdx.x;
    __shared__ float As[16 * TSP];
    __shared__ float Bs[16 * TSP];
    __shared__ float mu[16], rstd[16];

    {   // stage A = h1; compute residual row stats
        int r = tid >> 4, seg = tid & 15;
        int row = row0 + r;
        #pragma unroll
        for (int i = 0; i < 2; i++) {
            int k = seg * 8 + i * 4;
            *(float4*)&As[r * TSP + k] = *(const float4*)(h1 + (size_t)row * HH + k);
        }
        float s = 0.f, s2 = 0.f;
        #pragma unroll
        for (int i = 0; i < 2; i++) {
            int k = seg * 8 + i * 4;
            float4 q4 = *(const float4*)(Qin + (size_t)row * HH + k);
            float4 a4 = *(const float4*)(att + (size_t)row * HH + k);
            float4 v = make_float4(q4.x + a4.x, q4.y + a4.y, q4.z + a4.z, q4.w + a4.w);
            s  += v.x + v.y + v.z + v.w;
            s2 += v.x * v.x + v.y * v.y + v.z * v.z + v.w * v.w;
        }
        #pragma unroll
        for (int off = 1; off < 16; off <<= 1) {
            s  += __shfl_xor(s, off);
            s2 += __shfl_xor(s2, off);
        }
        float mean = s * (1.f / HH);
        float var  = s2 * (1.f / HH) - mean * mean;
        if (seg == 0) { mu[r] = mean; rstd[r] = 1.f / sqrtf(var + 1e-8f); }
    }
    {   // stage B
        int j = tid >> 4, seg = tid & 15;
        *(float4*)&Bs[j * TSP + seg * 8]     = *(const float4*)(W2 + (size_t)(jb + j) * HH + seg * 8);
        *(float4*)&Bs[j * TSP + seg * 8 + 4] = *(const float4*)(W2 + (size_t)(jb + j) * HH + seg * 8 + 4);
    }
    __syncthreads();

    int m = tid >> 4, j = tid & 15;
    float acc = 0.f;
    const float* ar = &As[m * TSP];
    const float* br = &Bs[j * TSP];
    #pragma unroll 4
    for (int k4 = 0; k4 < 32; k4++) {
        float4 a = *(const float4*)(ar + k4 * 4);
        float4 b = *(const float4*)(br + k4 * 4);
        acc += a.x * b.x + a.y * b.y + a.z * b.z + a.w * b.w;
    }
    int row = row0 + m;
    int col = jb + j;
    float resid = Qin[(size_t)row * HH + col] + att[(size_t)row * HH + col];
    float y = (resid - mu[m]) * rstd[m] * g[col] + bia[col];
    float o = acc + b2[col] + y;
    if (log_seqs[row] == 0) o = 0.f;
    out[(size_t)row * HH + col] = o;
}

// ===== fused last-LN + pos/neg logits: one block per row ==================
__global__ void k_lnlogits(const float* __restrict__ seqs,
                           const float* __restrict__ g, const float* __restrict__ bia,
                           const float* __restrict__ item_emb,
                           const int* __restrict__ pos, const int* __restrict__ neg,
                           float* __restrict__ out) {
    int row = blockIdx.x;
    int h = threadIdx.x;
    float v = seqs[(size_t)row * HH + h];
    float s = v, s2 = v * v;
    for (int off = 32; off; off >>= 1) {
        s  += __shfl_xor(s, off);
        s2 += __shfl_xor(s2, off);
    }
    __shared__ float r1[2], r2[2];
    if ((h & 63) == 0) { r1[h >> 6] = s; r2[h >> 6] = s2; }
    __syncthreads();
    float mean = (r1[0] + r1[1]) * (1.f / HH);
    float var  = (r2[0] + r2[1]) * (1.f / HH) - mean * mean;
    float inv = 1.f / sqrtf(var + 1e-8f);
    float f = (v - mean) * inv * g[h] + bia[h];

    int ip = pos[row], in_ = neg[row];
    float vp = f * item_emb[(size_t)ip * HH + h];
    float vn = f * item_emb[(size_t)in_ * HH + h];
    for (int off = 32; off; off >>= 1) {
        vp += __shfl_xor(vp, off);
        vn += __shfl_xor(vn, off);
    }
    __shared__ float rp[2], rn[2];
    if ((h & 63) == 0) { rp[h >> 6] = vp; rn[h >> 6] = vn; }
    __syncthreads();
    if (h == 0) {
        out[row]      = rp[0] + rp[1];
        out[BL + row] = rn[0] + rn[1];
    }
}

extern "C" void kernel_launch(void* const* d_in, const int* in_sizes, int n_in,
                              void* d_out, int out_size, void* d_ws, size_t ws_size,
                              hipStream_t stream) {
    const int* log_seqs   = (const int*)d_in[1];
    const int* tm         = (const int*)d_in[2];
    const int* pos_seqs   = (const int*)d_in[3];
    const int* neg_seqs   = (const int*)d_in[4];
    const float* item_emb = (const float*)d_in[5];
    const float* posK     = (const float*)d_in[6];
    const float* posV     = (const float*)d_in[7];
    const float* timeK    = (const float*)d_in[8];
    const float* timeV    = (const float*)d_in[9];
    const float* attn_g   = (const float*)d_in[10];
    const float* attn_b   = (const float*)d_in[11];
    const float* Wq       = (const float*)d_in[12];
    const float* bq       = (const float*)d_in[13];
    const float* Wk       = (const float*)d_in[14];
    const float* bk       = (const float*)d_in[15];
    const float* Wv       = (const float*)d_in[16];
    const float* bv       = (const float*)d_in[17];
    const float* fwd_g    = (const float*)d_in[18];
    const float* fwd_b    = (const float*)d_in[19];
    const float* W1       = (const float*)d_in[20];
    const float* b1       = (const float*)d_in[21];
    const float* W2       = (const float*)d_in[22];
    const float* b2       = (const float*)d_in[23];
    const float* last_g   = (const float*)d_in[24];
    const float* last_b   = (const float*)d_in[25];

    float* seqs = (float*)d_ws;            // 7 x B*L*H f32 = ~5.7 MB
    float* Qin  = seqs + (size_t)BL * HH;
    float* Qb   = Qin  + (size_t)BL * HH;
    float* Kb   = Qb   + (size_t)BL * HH;
    float* Vb   = Kb   + (size_t)BL * HH;
    float* att  = Vb   + (size_t)BL * HH;
    float* h1   = att  + (size_t)BL * HH;

    for (int i = 0; i < NBLK; i++) {
        k_qkv_gemm<<<1200, 256, 0, stream>>>(i == 0 ? nullptr : seqs, log_seqs, item_emb,
                                             attn_g + i * HH, attn_b + i * HH,
                                             Wq + (size_t)i * HH * HH, bq + i * HH,
                                             Wk + (size_t)i * HH * HH, bk + i * HH,
                                             Wv + (size_t)i * HH * HH, bv + i * HH,
                                             posK, posV, Qin, Qb, Kb, Vb);
        k_attn<<<NQT * 32, 256, 0, stream>>>(Qb, Kb, Vb, timeK, timeV, tm, att);
        k_ff1<<<800, 256, 0, stream>>>(Qin, att, fwd_g + i * HH, fwd_b + i * HH,
                                       W1 + (size_t)i * HH * HH, b1 + i * HH, h1);
        k_ff2<<<800, 256, 0, stream>>>(h1, Qin, att, fwd_g + i * HH, fwd_b + i * HH,
                                       W2 + (size_t)i * HH * HH, b2 + i * HH,
                                       log_seqs, seqs);
    }
    k_lnlogits<<<BL, HH, 0, stream>>>(seqs, last_g, last_b, item_emb,
                                      pos_seqs, neg_seqs, (float*)d_out);
}

// Round 4
// 235.128 us; speedup vs baseline: 3.1952x; 1.0053x over previous
//
#include <hip/hip_runtime.h>

#define BB 8
#define LL 200
#define HH 128
#define NHEAD 4
#define HDIM 32
#define NBLK 2
#define BL (BB * LL)
#define NT 257            // TIME_SPAN+1
#define QT 8              // attn queries per tile
#define NQT 25            // 200/8
#define SSP 208           // attn score row stride
#define KTP 66            // attn KstT row stride
#define TSP 132           // GEMM tile row stride [r][k]

static constexpr float SQRT_H    = 11.313708498984761f;   // sqrt(128)
static constexpr float INV_SCALE = 0.17677669529663687f;  // 1/sqrt(32)
static constexpr float PADV      = -4294967295.0f;        // -2^32+1

// ===== QKV GEMM v2: 300 blocks, each = (mt, group of 4 col-tiles) =========
// Stage A (+LN for Q groups) ONCE, then 4 B-tiles double-buffered with
// reg-prefetch issued before the dot (async issue-early/write-late).
__global__ void k_qkv_gemm(const float* __restrict__ seqs_in,
                           const int* __restrict__ log_seqs,
                           const float* __restrict__ item_emb,
                           const float* __restrict__ g, const float* __restrict__ bia,
                           const float* __restrict__ Wq, const float* __restrict__ bq,
                           const float* __restrict__ Wk, const float* __restrict__ bk,
                           const float* __restrict__ Wv, const float* __restrict__ bv,
                           const float* __restrict__ posK, const float* __restrict__ posV,
                           float* __restrict__ Qin, float* __restrict__ Q,
                           float* __restrict__ K, float* __restrict__ V) {
    int mt = blockIdx.x / 6, ntg = blockIdx.x % 6;
    int nt0 = ntg * 4;                 // 4 consecutive nt tiles, same matsel
    int matsel = nt0 >> 3;             // 0=Q 1=K 2=V
    int jb0 = (nt0 & 7) * 16;
    int row0 = mt * 32;
    int tid = threadIdx.x;
    __shared__ float As[32 * TSP];     // 16.9 KB [m][k]
    __shared__ float Bs[2][16 * TSP];  // 2 x 8.4 KB [j][k]

    {   // stage A: 32 rows x 128, 8 threads/row; LN for Q-groups (once)
        int r = tid >> 3, seg = tid & 7;
        int row = row0 + r;
        float4 vv[4];
        if (seqs_in) {
            #pragma unroll
            for (int i = 0; i < 4; i++)
                vv[i] = *(const float4*)(seqs_in + (size_t)row * HH + seg * 16 + i * 4);
        } else {
            int idx = log_seqs[row];
            if (idx == 0) {
                #pragma unroll
                for (int i = 0; i < 4; i++) vv[i] = make_float4(0.f, 0.f, 0.f, 0.f);
            } else {
                #pragma unroll
                for (int i = 0; i < 4; i++) {
                    float4 e = *(const float4*)(item_emb + (size_t)idx * HH + seg * 16 + i * 4);
                    vv[i] = make_float4(e.x * SQRT_H, e.y * SQRT_H, e.z * SQRT_H, e.w * SQRT_H);
                }
            }
        }
        if (matsel == 0) {
            float s = 0.f, s2 = 0.f;
            #pragma unroll
            for (int i = 0; i < 4; i++) {
                s  += vv[i].x + vv[i].y + vv[i].z + vv[i].w;
                s2 += vv[i].x * vv[i].x + vv[i].y * vv[i].y + vv[i].z * vv[i].z + vv[i].w * vv[i].w;
            }
            #pragma unroll
            for (int off = 1; off < 8; off <<= 1) {
                s  += __shfl_xor(s, off);
                s2 += __shfl_xor(s2, off);
            }
            float mean = s * (1.f / HH);
            float var  = s2 * (1.f / HH) - mean * mean;
            float inv  = 1.f / sqrtf(var + 1e-8f);
            #pragma unroll
            for (int i = 0; i < 4; i++) {
                int k = seg * 16 + i * 4;
                float4 g4 = *(const float4*)(g + k);
                float4 b4 = *(const float4*)(bia + k);
                float4 y;
                y.x = (vv[i].x - mean) * inv * g4.x + b4.x;
                y.y = (vv[i].y - mean) * inv * g4.y + b4.y;
                y.z = (vv[i].z - mean) * inv * g4.z + b4.z;
                y.w = (vv[i].w - mean) * inv * g4.w + b4.w;
                *(float4*)&As[r * TSP + k] = y;
                if (nt0 == 0) *(float4*)(Qin + (size_t)row * HH + k) = y;
            }
        } else {
            #pragma unroll
            for (int i = 0; i < 4; i++)
                *(float4*)&As[r * TSP + seg * 16 + i * 4] = vv[i];
        }
    }
    const float* W = (matsel == 0) ? Wq : (matsel == 1) ? Wk : Wv;
    int j = tid >> 4, seg16 = tid & 15;
    // prefetch B tile 0 and commit to Bs[0]
    float4 w0 = *(const float4*)(W + (size_t)(jb0 + j) * HH + seg16 * 8);
    float4 w1 = *(const float4*)(W + (size_t)(jb0 + j) * HH + seg16 * 8 + 4);
    *(float4*)&Bs[0][j * TSP + seg16 * 8]     = w0;
    *(float4*)&Bs[0][j * TSP + seg16 * 8 + 4] = w1;
    __syncthreads();

    int m = tid >> 3, jg = tid & 7;    // 2 output cols per thread
    const float* ar = &As[m * TSP];
    #pragma unroll
    for (int it = 0; it < 4; it++) {
        int jb = jb0 + it * 16;
        if (it < 3) {   // issue next tile's loads BEFORE the dot
            int jbn = jb0 + (it + 1) * 16;
            w0 = *(const float4*)(W + (size_t)(jbn + j) * HH + seg16 * 8);
            w1 = *(const float4*)(W + (size_t)(jbn + j) * HH + seg16 * 8 + 4);
        }
        float acc0 = 0.f, acc1 = 0.f;
        const float* b0r = &Bs[it & 1][(jg * 2) * TSP];
        const float* b1r = &Bs[it & 1][(jg * 2 + 1) * TSP];
        #pragma unroll 4
        for (int k4 = 0; k4 < 32; k4++) {
            float4 a  = *(const float4*)(ar + k4 * 4);
            float4 b0 = *(const float4*)(b0r + k4 * 4);
            float4 b1 = *(const float4*)(b1r + k4 * 4);
            acc0 += a.x * b0.x + a.y * b0.y + a.z * b0.z + a.w * b0.w;
            acc1 += a.x * b1.x + a.y * b1.y + a.z * b1.z + a.w * b1.w;
        }
        int row = row0 + m;
        int col = jb + jg * 2;
        int l = row % LL;
        if (matsel == 0) {
            float2 bb = *(const float2*)(bq + col);
            *(float2*)(Q + (size_t)row * HH + col) =
                make_float2((acc0 + bb.x) * INV_SCALE, (acc1 + bb.y) * INV_SCALE);
        } else if (matsel == 1) {
            float2 bb = *(const float2*)(bk + col);
            float2 pk = *(const float2*)(posK + (size_t)l * HH + col);
            *(float2*)(K + (size_t)row * HH + col) =
                make_float2(acc0 + bb.x + pk.x, acc1 + bb.y + pk.y);
        } else {
            float2 bb = *(const float2*)(bv + col);
            float2 pv = *(const float2*)(posV + (size_t)l * HH + col);
            *(float2*)(V + (size_t)row * HH + col) =
                make_float2(acc0 + bb.x + pv.x, acc1 + bb.y + pv.y);
        }
        if (it < 3) {   // write-late: vmcnt wait lands here, after the dot
            *(float4*)&Bs[(it + 1) & 1][j * TSP + seg16 * 8]     = w0;
            *(float4*)&Bs[(it + 1) & 1][j * TSP + seg16 * 8 + 4] = w1;
        }
        __syncthreads();
    }
}

// ===== attention v4: async-split chunk pipeline (issue-early/write-late) ===
// Per chunk: load(c+1)->regs; dot(c); ds_write(c+1); barrier. The vmcnt wait
// now sits AFTER the dot, so global latency hides under LDS compute.
__global__ void k_attn(const float* __restrict__ Q, const float* __restrict__ K,
                       const float* __restrict__ V,
                       const float* __restrict__ timeK, const float* __restrict__ timeV,
                       const int* __restrict__ tm,
                       float* __restrict__ att) {
    int bn = blockIdx.x & 31;
    int b = bn >> 2, n = bn & 3;
    int qt = (NQT - 1) - (blockIdx.x >> 5);
    int q0 = qt * QT;
    int kmax = q0 + QT - 1;
    int tid = threadIdx.x;
    int wv = tid >> 6, ln = tid & 63;

    __shared__ float KstT[2][HDIM * KTP];  // 2 x 8.4 KB staging (dbuf)
    __shared__ float DTW[QT * NT];         // 8.2 KB DT table
    __shared__ float Ssc[QT * SSP];        // 6.7 KB scores -> P
    __shared__ float Ost[QT * HDIM];       // 1.0 KB
    __shared__ int   tmst[QT * LL];        // 6.4 KB

    Ost[tid] = 0.f;
    #pragma unroll
    for (int qi = 0; qi < QT; qi++)
        if (tid < LL)
            tmst[qi * LL + tid] = tm[((size_t)(b * LL + q0 + qi)) * LL + tid];

    int k2 = tid & 31, qi_c = tid >> 5;
    int q = q0 + qi_c;

    float qreg[HDIM];
    {
        const float* qp = Q + ((size_t)(b * LL + q)) * HH + n * HDIM;
        #pragma unroll
        for (int i = 0; i < 8; i++) {
            float4 v = *(const float4*)(qp + i * 4);
            qreg[i * 4 + 0] = v.x; qreg[i * 4 + 1] = v.y;
            qreg[i * 4 + 2] = v.z; qreg[i * 4 + 3] = v.w;
        }
    }

    const int nchS = (kmax >> 6) + 1;      // K chunks (1..4)
    const int ncht = 5 + nchS;             // total chunks

    int rS = tid >> 3, d4 = tid & 7;       // staging coords: rows rS, rS+32

    // issue chunk-c global loads into registers (2 x float4 per thread)
    auto ld_chunk = [&](int c, float4& f0, float4& f1) {
        f0 = make_float4(0.f, 0.f, 0.f, 0.f);
        f1 = make_float4(0.f, 0.f, 0.f, 0.f);
        if (c < 5) {
            int tau = c * 64 + rS;
            if (tau < NT)      f0 = *(const float4*)(timeK + (size_t)tau * HH + n * HDIM + d4 * 4);
            if (tau + 32 < NT) f1 = *(const float4*)(timeK + (size_t)(tau + 32) * HH + n * HDIM + d4 * 4);
        } else {
            int k = (c - 5) * 64 + rS;
            if (k < LL)      f0 = *(const float4*)(K + ((size_t)(b * LL + k)) * HH + n * HDIM + d4 * 4);
            if (k + 32 < LL) f1 = *(const float4*)(K + ((size_t)(b * LL + k + 32)) * HH + n * HDIM + d4 * 4);
        }
    };
    auto wr_chunk = [&](float4 f0, float4 f1, float* buf) {
        buf[(d4 * 4 + 0) * KTP + rS] = f0.x;
        buf[(d4 * 4 + 1) * KTP + rS] = f0.y;
        buf[(d4 * 4 + 2) * KTP + rS] = f0.z;
        buf[(d4 * 4 + 3) * KTP + rS] = f0.w;
        buf[(d4 * 4 + 0) * KTP + rS + 32] = f1.x;
        buf[(d4 * 4 + 1) * KTP + rS + 32] = f1.y;
        buf[(d4 * 4 + 2) * KTP + rS + 32] = f1.z;
        buf[(d4 * 4 + 3) * KTP + rS + 32] = f1.w;
    };

    {
        float4 c0, c1;
        ld_chunk(0, c0, c1);
        wr_chunk(c0, c1, KstT[0]);
    }
    __syncthreads();
    for (int c = 0; c < ncht; c++) {
        float4 n0, n1;
        bool more = (c + 1 < ncht);
        if (more) ld_chunk(c + 1, n0, n1);   // issue-early
        const float* buf = KstT[c & 1];
        float a0 = 0.f, a1 = 0.f;
        #pragma unroll 4
        for (int d = 0; d < HDIM; d++) {
            float qv = qreg[d];
            float2 kv = *(const float2*)&buf[d * KTP + k2 * 2];
            a0 += qv * kv.x; a1 += qv * kv.y;
        }
        if (c < 5) {
            int tau0 = c * 64 + k2 * 2;
            if (tau0 < NT)     DTW[qi_c * NT + tau0]     = a0;
            if (tau0 + 1 < NT) DTW[qi_c * NT + tau0 + 1] = a1;
        } else {
            int k0 = (c - 5) * 64 + k2 * 2;
            if (k0 <= kmax)     Ssc[qi_c * SSP + k0]     = a0;   // raw QK; DT added in softmax
            if (k0 + 1 <= kmax) Ssc[qi_c * SSP + k0 + 1] = a1;
        }
        if (more) wr_chunk(n0, n1, KstT[(c + 1) & 1]);   // write-late
        __syncthreads();
    }

    // softmax with fused DT gather (LDS): sv = QK + DT[tm[k]]
    for (int rr = 0; rr < 2; rr++) {
        int qi = wv + rr * 4;
        int qq = q0 + qi;
        float sv[4];
        float m = PADV;
        #pragma unroll
        for (int jj = 0; jj < 4; jj++) {
            int k = ln + 64 * jj;
            sv[jj] = (k <= qq) ? (Ssc[qi * SSP + k] + DTW[qi * NT + tmst[qi * LL + k]]) : PADV;
            m = fmaxf(m, sv[jj]);
        }
        for (int off = 32; off; off >>= 1) m = fmaxf(m, __shfl_xor(m, off));
        float sum = 0.f;
        #pragma unroll
        for (int jj = 0; jj < 4; jj++) {
            int k = ln + 64 * jj;
            sv[jj] = (k <= qq) ? __expf(sv[jj] - m) : 0.f;
            sum += sv[jj];
        }
        for (int off = 32; off; off >>= 1) sum += __shfl_xor(sum, off);
        float inv = 1.f / sum;
        #pragma unroll
        for (int jj = 0; jj < 4; jj++) {
            int k = ln + 64 * jj;
            if (k < SSP) Ssc[qi * SSP + k] = (k <= qq) ? sv[jj] * inv : 0.f;
        }
    }
    __syncthreads();

    // O = P@(Vh + timeVh[tm]) — per-(qi,k) timeV row read is lane-coalesced
    int d = tid & 31, kg = tid >> 5;
    float acc[QT] = {0,0,0,0,0,0,0,0};
    const float* vb  = V + ((size_t)(b * LL)) * HH + n * HDIM + d;
    const float* tvb = timeV + n * HDIM + d;
    for (int k = kg; k <= kmax; k += 8) {
        float v = vb[(size_t)k * HH];
        #pragma unroll
        for (int qi = 0; qi < QT; qi++) {
            float p  = Ssc[qi * SSP + k];
            float tv = tvb[(size_t)tmst[qi * LL + k] * HH];
            acc[qi] += p * (v + tv);
        }
    }
    #pragma unroll
    for (int qi = 0; qi < QT; qi++) atomicAdd(&Ost[qi * HDIM + d], acc[qi]);
    __syncthreads();
    {
        int qi = tid >> 5;
        att[((size_t)(b * LL + q0 + qi)) * HH + n * HDIM + (tid & 31)] = Ost[tid];
    }
}

// ===== FF1 v2: 200 blocks x 4 col-tiles; LN once, B dbuf + reg prefetch ===
__global__ void k_ff1(const float* __restrict__ Qin, const float* __restrict__ att,
                      const float* __restrict__ g, const float* __restrict__ bia,
                      const float* __restrict__ W1, const float* __restrict__ b1,
                      float* __restrict__ h1) {
    int mt = blockIdx.x >> 1, jb0 = (blockIdx.x & 1) * 64;
    int row0 = mt * 16;
    int tid = threadIdx.x;
    __shared__ float As[16 * TSP];
    __shared__ float Bs[2][16 * TSP];

    {   // stage A = LN(Qin+att), 16 threads/row — computed ONCE per 4 tiles
        int r = tid >> 4, seg = tid & 15;
        int row = row0 + r;
        float4 vv[2];
        #pragma unroll
        for (int i = 0; i < 2; i++) {
            int k = seg * 8 + i * 4;
            float4 q4 = *(const float4*)(Qin + (size_t)row * HH + k);
            float4 a4 = *(const float4*)(att + (size_t)row * HH + k);
            vv[i] = make_float4(q4.x + a4.x, q4.y + a4.y, q4.z + a4.z, q4.w + a4.w);
        }
        float s = 0.f, s2 = 0.f;
        #pragma unroll
        for (int i = 0; i < 2; i++) {
            s  += vv[i].x + vv[i].y + vv[i].z + vv[i].w;
            s2 += vv[i].x * vv[i].x + vv[i].y * vv[i].y + vv[i].z * vv[i].z + vv[i].w * vv[i].w;
        }
        #pragma unroll
        for (int off = 1; off < 16; off <<= 1) {
            s  += __shfl_xor(s, off);
            s2 += __shfl_xor(s2, off);
        }
        float mean = s * (1.f / HH);
        float var  = s2 * (1.f / HH) - mean * mean;
        float inv  = 1.f / sqrtf(var + 1e-8f);
        #pragma unroll
        for (int i = 0; i < 2; i++) {
            int k = seg * 8 + i * 4;
            float4 g4 = *(const float4*)(g + k);
            float4 b4 = *(const float4*)(bia + k);
            float4 y;
            y.x = (vv[i].x - mean) * inv * g4.x + b4.x;
            y.y = (vv[i].y - mean) * inv * g4.y + b4.y;
            y.z = (vv[i].z - mean) * inv * g4.z + b4.z;
            y.w = (vv[i].w - mean) * inv * g4.w + b4.w;
            *(float4*)&As[r * TSP + k] = y;
        }
    }
    int j = tid >> 4, seg16 = tid & 15;
    float4 w0 = *(const float4*)(W1 + (size_t)(jb0 + j) * HH + seg16 * 8);
    float4 w1 = *(const float4*)(W1 + (size_t)(jb0 + j) * HH + seg16 * 8 + 4);
    *(float4*)&Bs[0][j * TSP + seg16 * 8]     = w0;
    *(float4*)&Bs[0][j * TSP + seg16 * 8 + 4] = w1;
    __syncthreads();

    int m = tid >> 4, jj = tid & 15;
    const float* ar = &As[m * TSP];
    #pragma unroll
    for (int it = 0; it < 4; it++) {
        int jb = jb0 + it * 16;
        if (it < 3) {
            int jbn = jb0 + (it + 1) * 16;
            w0 = *(const float4*)(W1 + (size_t)(jbn + j) * HH + seg16 * 8);
            w1 = *(const float4*)(W1 + (size_t)(jbn + j) * HH + seg16 * 8 + 4);
        }
        float acc = 0.f;
        const float* br = &Bs[it & 1][jj * TSP];
        #pragma unroll 4
        for (int k4 = 0; k4 < 32; k4++) {
            float4 a = *(const float4*)(ar + k4 * 4);
            float4 b = *(const float4*)(br + k4 * 4);
            acc += a.x * b.x + a.y * b.y + a.z * b.z + a.w * b.w;
        }
        int col = jb + jj;
        float t = acc + b1[col];
        h1[(size_t)(row0 + m) * HH + col] = t > 0.f ? t : 0.f;
        if (it < 3) {
            *(float4*)&Bs[(it + 1) & 1][j * TSP + seg16 * 8]     = w0;
            *(float4*)&Bs[(it + 1) & 1][j * TSP + seg16 * 8 + 4] = w1;
        }
        __syncthreads();
    }
}

// ===== FF2 v2: 200 blocks x 4 col-tiles; stats once, B dbuf + prefetch ====
__global__ void k_ff2(const float* __restrict__ h1,
                      const float* __restrict__ Qin, const float* __restrict__ att,
                      const float* __restrict__ g, const float* __restrict__ bia,
                      const float* __restrict__ W2, const float* __restrict__ b2,
                      const int* __restrict__ log_seqs,
                      float* __restrict__ out) {
    int mt = blockIdx.x >> 1, jb0 = (blockIdx.x & 1) * 64;
    int row0 = mt * 16;
    int tid = threadIdx.x;
    __shared__ float As[16 * TSP];
    __shared__ float Bs[2][16 * TSP];
    __shared__ float mu[16], rstd[16];

    {   // stage A = h1; residual row stats ONCE per 4 tiles
        int r = tid >> 4, seg = tid & 15;
        int row = row0 + r;
        #pragma unroll
        for (int i = 0; i < 2; i++) {
            int k = seg * 8 + i * 4;
            *(float4*)&As[r * TSP + k] = *(const float4*)(h1 + (size_t)row * HH + k);
        }
        float s = 0.f, s2 = 0.f;
        #pragma unroll
        for (int i = 0; i < 2; i++) {
            int k = seg * 8 + i * 4;
            float4 q4 = *(const float4*)(Qin + (size_t)row * HH + k);
            float4 a4 = *(const float4*)(att + (size_t)row * HH + k);
            float4 v = make_float4(q4.x + a4.x, q4.y + a4.y, q4.z + a4.z, q4.w + a4.w);
            s  += v.x + v.y + v.z + v.w;
            s2 += v.x * v.x + v.y * v.y + v.z * v.z + v.w * v.w;
        }
        #pragma unroll
        for (int off = 1; off < 16; off <<= 1) {
            s  += __shfl_xor(s, off);
            s2 += __shfl_xor(s2, off);
        }
        float mean = s * (1.f / HH);
        float var  = s2 * (1.f / HH) - mean * mean;
        if (seg == 0) { mu[r] = mean; rstd[r] = 1.f / sqrtf(var + 1e-8f); }
    }
    int j = tid >> 4, seg16 = tid & 15;
    float4 w0 = *(const float4*)(W2 + (size_t)(jb0 + j) * HH + seg16 * 8);
    float4 w1 = *(const float4*)(W2 + (size_t)(jb0 + j) * HH + seg16 * 8 + 4);
    *(float4*)&Bs[0][j * TSP + seg16 * 8]     = w0;
    *(float4*)&Bs[0][j * TSP + seg16 * 8 + 4] = w1;
    __syncthreads();

    int m = tid >> 4, jj = tid & 15;
    const float* ar = &As[m * TSP];
    #pragma unroll
    for (int it = 0; it < 4; it++) {
        int jb = jb0 + it * 16;
        if (it < 3) {
            int jbn = jb0 + (it + 1) * 16;
            w0 = *(const float4*)(W2 + (size_t)(jbn + j) * HH + seg16 * 8);
            w1 = *(const float4*)(W2 + (size_t)(jbn + j) * HH + seg16 * 8 + 4);
        }
        float acc = 0.f;
        const float* br = &Bs[it & 1][jj * TSP];
        #pragma unroll 4
        for (int k4 = 0; k4 < 32; k4++) {
            float4 a = *(const float4*)(ar + k4 * 4);
            float4 b = *(const float4*)(br + k4 * 4);
            acc += a.x * b.x + a.y * b.y + a.z * b.z + a.w * b.w;
        }
        int row = row0 + m;
        int col = jb + jj;
        float resid = Qin[(size_t)row * HH + col] + att[(size_t)row * HH + col];
        float y = (resid - mu[m]) * rstd[m] * g[col] + bia[col];
        float o = acc + b2[col] + y;
        if (log_seqs[row] == 0) o = 0.f;
        out[(size_t)row * HH + col] = o;
        if (it < 3) {
            *(float4*)&Bs[(it + 1) & 1][j * TSP + seg16 * 8]     = w0;
            *(float4*)&Bs[(it + 1) & 1][j * TSP + seg16 * 8 + 4] = w1;
        }
        __syncthreads();
    }
}

// ===== fused last-LN + pos/neg logits: one block per row ==================
__global__ void k_lnlogits(const float* __restrict__ seqs,
                           const float* __restrict__ g, const float* __restrict__ bia,
                           const float* __restrict__ item_emb,
                           const int* __restrict__ pos, const int* __restrict__ neg,
                           float* __restrict__ out) {
    int row = blockIdx.x;
    int h = threadIdx.x;
    float v = seqs[(size_t)row * HH + h];
    float s = v, s2 = v * v;
    for (int off = 32; off; off >>= 1) {
        s  += __shfl_xor(s, off);
        s2 += __shfl_xor(s2, off);
    }
    __shared__ float r1[2], r2[2];
    if ((h & 63) == 0) { r1[h >> 6] = s; r2[h >> 6] = s2; }
    __syncthreads();
    float mean = (r1[0] + r1[1]) * (1.f / HH);
    float var  = (r2[0] + r2[1]) * (1.f / HH) - mean * mean;
    float inv = 1.f / sqrtf(var + 1e-8f);
    float f = (v - mean) * inv * g[h] + bia[h];

    int ip = pos[row], in_ = neg[row];
    float vp = f * item_emb[(size_t)ip * HH + h];
    float vn = f * item_emb[(size_t)in_ * HH + h];
    for (int off = 32; off; off >>= 1) {
        vp += __shfl_xor(vp, off);
        vn += __shfl_xor(vn, off);
    }
    __shared__ float rp[2], rn[2];
    if ((h & 63) == 0) { rp[h >> 6] = vp; rn[h >> 6] = vn; }
    __syncthreads();
    if (h == 0) {
        out[row]      = rp[0] + rp[1];
        out[BL + row] = rn[0] + rn[1];
    }
}

extern "C" void kernel_launch(void* const* d_in, const int* in_sizes, int n_in,
                              void* d_out, int out_size, void* d_ws, size_t ws_size,
                              hipStream_t stream) {
    const int* log_seqs   = (const int*)d_in[1];
    const int* tm         = (const int*)d_in[2];
    const int* pos_seqs   = (const int*)d_in[3];
    const int* neg_seqs   = (const int*)d_in[4];
    const float* item_emb = (const float*)d_in[5];
    const float* posK     = (const float*)d_in[6];
    const float* posV     = (const float*)d_in[7];
    const float* timeK    = (const float*)d_in[8];
    const float* timeV    = (const float*)d_in[9];
    const float* attn_g   = (const float*)d_in[10];
    const float* attn_b   = (const float*)d_in[11];
    const float* Wq       = (const float*)d_in[12];
    const float* bq       = (const float*)d_in[13];
    const float* Wk       = (const float*)d_in[14];
    const float* bk       = (const float*)d_in[15];
    const float* Wv       = (const float*)d_in[16];
    const float* bv       = (const float*)d_in[17];
    const float* fwd_g    = (const float*)d_in[18];
    const float* fwd_b    = (const float*)d_in[19];
    const float* W1       = (const float*)d_in[20];
    const float* b1       = (const float*)d_in[21];
    const float* W2       = (const float*)d_in[22];
    const float* b2       = (const float*)d_in[23];
    const float* last_g   = (const float*)d_in[24];
    const float* last_b   = (const float*)d_in[25];

    float* seqs = (float*)d_ws;            // 7 x B*L*H f32 = ~5.7 MB
    float* Qin  = seqs + (size_t)BL * HH;
    float* Qb   = Qin  + (size_t)BL * HH;
    float* Kb   = Qb   + (size_t)BL * HH;
    float* Vb   = Kb   + (size_t)BL * HH;
    float* att  = Vb   + (size_t)BL * HH;
    float* h1   = att  + (size_t)BL * HH;

    for (int i = 0; i < NBLK; i++) {
        k_qkv_gemm<<<300, 256, 0, stream>>>(i == 0 ? nullptr : seqs, log_seqs, item_emb,
                                            attn_g + i * HH, attn_b + i * HH,
                                            Wq + (size_t)i * HH * HH, bq + i * HH,
                                            Wk + (size_t)i * HH * HH, bk + i * HH,
                                            Wv + (size_t)i * HH * HH, bv + i * HH,
                                            posK, posV, Qin, Qb, Kb, Vb);
        k_attn<<<NQT * 32, 256, 0, stream>>>(Qb, Kb, Vb, timeK, timeV, tm, att);
        k_ff1<<<200, 256, 0, stream>>>(Qin, att, fwd_g + i * HH, fwd_b + i * HH,
                                       W1 + (size_t)i * HH * HH, b1 + i * HH, h1);
        k_ff2<<<200, 256, 0, stream>>>(h1, Qin, att, fwd_g + i * HH, fwd_b + i * HH,
                                       W2 + (size_t)i * HH * HH, b2 + i * HH,
                                       log_seqs, seqs);
    }
    k_lnlogits<<<BL, HH, 0, stream>>>(seqs, last_g, last_b, item_emb,
                                      pos_seqs, neg_seqs, (float*)d_out);
}